// Round 1
// baseline (428.532 us; speedup 1.0000x reference)
//
#include <hip/hip_runtime.h>
#include <hip/hip_bf16.h>

#define HW_ 69696
#define W_ 264
#define H_ 264

// ---------------- Kernel A: roll(-4,-4) + 1x1 conv (96 -> 288), bf16 out ----------------
// GEMM: qkv[o][p] = sum_c w[o][c] * x[c][roll(p)], tile 96 outs x 64 px, 128 thr, 6x8 microtile
__global__ __launch_bounds__(128) void k_qkv(const float* __restrict__ x,
                                             const float* __restrict__ w,
                                             __hip_bfloat16* __restrict__ qkv) {
  __shared__ __align__(16) float wT[96 * 100];  // [oo][k], pitch 100
  __shared__ __align__(16) float xT[96 * 64];   // [k][j]
  __shared__ int rp[64];
  const int tid = threadIdx.x;
  const int pb = blockIdx.x;   // 0..1088 (64 px each)
  const int oc = blockIdx.y;   // 0..2   (96 outputs each)

  if (tid < 64) {
    int p = pb * 64 + tid;
    int y = p / W_;
    int xx = p - y * W_;
    int y2 = y + 4; if (y2 >= H_) y2 -= H_;
    int x2 = xx + 4; if (x2 >= W_) x2 -= W_;
    rp[tid] = y2 * W_ + x2;
  }
  __syncthreads();

  for (int l = tid; l < 96 * 96; l += 128) {
    int oo = l / 96;
    int k = l - oo * 96;
    wT[oo * 100 + k] = w[(oc * 96 + oo) * 96 + k];
  }
  for (int l = tid; l < 96 * 64; l += 128) {
    int k = l >> 6;
    int j = l & 63;
    xT[l] = x[k * HW_ + rp[j]];
  }
  __syncthreads();

  const int px8 = (tid & 7) * 8;
  const int oy = (tid >> 3) * 6;
  float acc[6][8];
#pragma unroll
  for (int i = 0; i < 6; ++i)
#pragma unroll
    for (int j = 0; j < 8; ++j) acc[i][j] = 0.f;

  for (int k4 = 0; k4 < 96; k4 += 4) {
    float a_s[6][4];
#pragma unroll
    for (int i = 0; i < 6; ++i) {
      float4 t4 = *(const float4*)&wT[(oy + i) * 100 + k4];
      a_s[i][0] = t4.x; a_s[i][1] = t4.y; a_s[i][2] = t4.z; a_s[i][3] = t4.w;
    }
#pragma unroll
    for (int kk = 0; kk < 4; ++kk) {
      float4 b0 = *(const float4*)&xT[(k4 + kk) * 64 + px8];
      float4 b1 = *(const float4*)&xT[(k4 + kk) * 64 + px8 + 4];
      float bb[8] = {b0.x, b0.y, b0.z, b0.w, b1.x, b1.y, b1.z, b1.w};
#pragma unroll
      for (int i = 0; i < 6; ++i) {
        float a = a_s[i][kk];
#pragma unroll
        for (int j = 0; j < 8; ++j) acc[i][j] += a * bb[j];
      }
    }
  }

#pragma unroll
  for (int i = 0; i < 6; ++i) {
    int o = oc * 96 + oy + i;
#pragma unroll
    for (int j = 0; j < 8; ++j) {
      qkv[o * HW_ + pb * 64 + px8 + j] = __float2bfloat16(acc[i][j]);
    }
  }
}

// ---------------- Kernel B: 3x3 depthwise conv, pad 1, 288 channels, bf16->bf16 ----------------
__global__ __launch_bounds__(256) void k_dw(const __hip_bfloat16* __restrict__ qkv,
                                            const float* __restrict__ dw,
                                            __hip_bfloat16* __restrict__ out) {
  const int ch = blockIdx.y;
  const int g = blockIdx.x * 256 + threadIdx.x;
  if (g >= HW_ / 4) return;       // 17424 groups of 4 px (264 % 4 == 0 -> same row)
  const int p0 = g * 4;
  const int y = p0 / W_;
  const int x0 = p0 - y * W_;
  const float* wk = dw + ch * 9;  // blockIdx-uniform -> scalar loads
  float wv[9];
#pragma unroll
  for (int tq = 0; tq < 9; ++tq) wv[tq] = wk[tq];
  const __hip_bfloat16* src = qkv + ch * HW_;
  float a0 = 0.f, a1 = 0.f, a2 = 0.f, a3 = 0.f;
#pragma unroll
  for (int dy = 0; dy < 3; ++dy) {
    int yy = y + dy - 1;
    if ((unsigned)yy < (unsigned)H_) {
      const __hip_bfloat16* row = src + yy * W_;
      float v[6];
#pragma unroll
      for (int e = 0; e < 6; ++e) {
        int cx = x0 - 1 + e;
        v[e] = ((unsigned)cx < (unsigned)W_) ? __bfloat162float(row[cx]) : 0.f;
      }
      float w0 = wv[dy * 3 + 0], w1 = wv[dy * 3 + 1], w2 = wv[dy * 3 + 2];
      a0 += w0 * v[0] + w1 * v[1] + w2 * v[2];
      a1 += w0 * v[1] + w1 * v[2] + w2 * v[3];
      a2 += w0 * v[2] + w1 * v[3] + w2 * v[4];
      a3 += w0 * v[3] + w1 * v[4] + w2 * v[5];
    }
  }
  __hip_bfloat16* dst = out + ch * HW_ + p0;
  dst[0] = __float2bfloat16(a0);
  dst[1] = __float2bfloat16(a1);
  dst[2] = __float2bfloat16(a2);
  dst[3] = __float2bfloat16(a3);
}

// ---------------- Kernel C: windowed channel attention ----------------
// one block (64 thr) per (window wi, tile t, head h). tout layout [t][96][64][64] fp32.
__global__ __launch_bounds__(64) void k_attn(const __hip_bfloat16* __restrict__ qd,
                                             const float* __restrict__ temp,
                                             float* __restrict__ tout) {
  __shared__ __align__(16) float qk[2 * 64 * 36];  // qsT/ksT token-major [m][c], pitch 36
  __shared__ __align__(16) float vsm[32 * 68];     // v channel-major [d][n], pitch 68
  __shared__ __align__(16) float att[32 * 36];     // attn [c][d], pitch 36
  __shared__ float invn[64];                       // invq[0:32], invk[32:64]
  const int tid = threadIdx.x;
  const int wi = blockIdx.x;   // 0..63
  const int t = blockIdx.y;    // 0..24
  const int h = blockIdx.z;    // 0..2
  const int i0 = (t / 5) * 50, j0 = (t % 5) * 50;
  const int wy = wi >> 3, wx = wi & 7;
  const int gy = i0 + wy * 8 + (tid >> 3);
  const int gx = j0 + wx * 8 + (tid & 7);
  const int gp = gy * W_ + gx;
  const int cb = h * 32;
  float* qsT = qk;
  float* ksT = qk + 64 * 36;

#pragma unroll 4
  for (int c = 0; c < 32; ++c) {
    qsT[tid * 36 + c] = __bfloat162float(qd[(cb + c) * HW_ + gp]);
    ksT[tid * 36 + c] = __bfloat162float(qd[(96 + cb + c) * HW_ + gp]);
    vsm[c * 68 + tid] = __bfloat162float(qd[(192 + cb + c) * HW_ + gp]);
  }
  __syncthreads();

  {  // row L2 norms (over 64 tokens)
    const float* bp = (tid < 32) ? qsT : ksT;
    const int r = tid & 31;
    float ss = 0.f;
    for (int m = 0; m < 64; ++m) {
      float v = bp[m * 36 + r];
      ss += v * v;
    }
    invn[tid] = 1.f / fmaxf(sqrtf(ss), 1e-12f);
  }
  __syncthreads();

  const float tscale = temp[h];
  {  // attn = relu((q^ k^T) * temp), 4x4 register tile per thread
    const int c4 = (tid & 7) * 4;
    const int d4 = (tid >> 3) * 4;
    float acc[4][4] = {};
    for (int m = 0; m < 64; ++m) {
      float4 qv = *(const float4*)&qsT[m * 36 + c4];
      float4 kv = *(const float4*)&ksT[m * 36 + d4];
      float qa[4] = {qv.x, qv.y, qv.z, qv.w};
      float ka[4] = {kv.x, kv.y, kv.z, kv.w};
#pragma unroll
      for (int i = 0; i < 4; ++i)
#pragma unroll
        for (int j = 0; j < 4; ++j) acc[i][j] += qa[i] * ka[j];
    }
#pragma unroll
    for (int i = 0; i < 4; ++i) {
      float iq = invn[c4 + i];
      float4 w4;
      w4.x = fmaxf(acc[i][0] * iq * invn[32 + d4 + 0] * tscale, 0.f);
      w4.y = fmaxf(acc[i][1] * iq * invn[32 + d4 + 1] * tscale, 0.f);
      w4.z = fmaxf(acc[i][2] * iq * invn[32 + d4 + 2] * tscale, 0.f);
      w4.w = fmaxf(acc[i][3] * iq * invn[32 + d4 + 3] * tscale, 0.f);
      *(float4*)&att[(c4 + i) * 36 + d4] = w4;
    }
  }
  __syncthreads();

  {  // out = attn @ v ; thread: 2 groups of 4 channels x 4 tokens
    const int n4 = (tid & 15) * 4;
    const int cg0 = (tid >> 4) * 4;
    float acc[2][4][4] = {};
    for (int db = 0; db < 8; ++db) {
      float4 vr[4];
#pragma unroll
      for (int r = 0; r < 4; ++r) vr[r] = *(const float4*)&vsm[(db * 4 + r) * 68 + n4];
#pragma unroll
      for (int gci = 0; gci < 2; ++gci) {
        int cbase = cg0 + gci * 16;
#pragma unroll
        for (int i = 0; i < 4; ++i) {
          float4 a4 = *(const float4*)&att[(cbase + i) * 36 + db * 4];
          float aa[4] = {a4.x, a4.y, a4.z, a4.w};
#pragma unroll
          for (int r = 0; r < 4; ++r) {
            acc[gci][i][0] += aa[r] * vr[r].x;
            acc[gci][i][1] += aa[r] * vr[r].y;
            acc[gci][i][2] += aa[r] * vr[r].z;
            acc[gci][i][3] += aa[r] * vr[r].w;
          }
        }
      }
    }
    const int ly = wy * 8 + (n4 >> 3);
    const int lx = wx * 8 + (n4 & 7);
    const int sp = ly * 64 + lx;
#pragma unroll
    for (int gci = 0; gci < 2; ++gci)
#pragma unroll
      for (int i = 0; i < 4; ++i) {
        int c = cb + cg0 + gci * 16 + i;
        float4 o4 = make_float4(acc[gci][i][0], acc[gci][i][1], acc[gci][i][2], acc[gci][i][3]);
        *(float4*)&tout[(t * 96 + c) * 4096 + sp] = o4;
      }
  }
}

// ---------------- Kernel D: overlap-average + 1x1 proj + roll(+4,+4), fp32 out ----------------
__global__ __launch_bounds__(128) void k_merge(const float* __restrict__ tout,
                                               const float* __restrict__ pw,
                                               float* __restrict__ out) {
  __shared__ __align__(16) float wT[96 * 100];  // [o][k] pitch 100
  __shared__ __align__(16) float pr[96 * 64];   // preds [k][j]
  const int tid = threadIdx.x;
  const int pb = blockIdx.x;

  for (int l = tid; l < 96 * 96; l += 128) {
    int oo = l / 96;
    int k = l - oo * 96;
    wT[oo * 100 + k] = pw[oo * 96 + k];
  }
  for (int l = tid; l < 96 * 64; l += 128) {
    int k = l >> 6;
    int j = l & 63;
    int p = pb * 64 + j;
    int y = p / W_;
    int xx = p - y * W_;
    int loy = (y >= 64) ? (y - 14) / 50 : 0;
    int hiy = y / 50; if (hiy > 4) hiy = 4;
    int lox = (xx >= 64) ? (xx - 14) / 50 : 0;
    int hix = xx / 50; if (hix > 4) hix = 4;
    float s = 0.f;
    int cnt = 0;
    for (int ty = loy; ty <= hiy; ++ty)
      for (int tx = lox; tx <= hix; ++tx) {
        s += tout[((ty * 5 + tx) * 96 + k) * 4096 + ((y - ty * 50) << 6) + (xx - tx * 50)];
        ++cnt;
      }
    pr[l] = s / (float)cnt;
  }
  __syncthreads();

  const int px8 = (tid & 7) * 8;
  const int oy = (tid >> 3) * 6;
  float acc[6][8];
#pragma unroll
  for (int i = 0; i < 6; ++i)
#pragma unroll
    for (int j = 0; j < 8; ++j) acc[i][j] = 0.f;

  for (int k4 = 0; k4 < 96; k4 += 4) {
    float a_s[6][4];
#pragma unroll
    for (int i = 0; i < 6; ++i) {
      float4 t4 = *(const float4*)&wT[(oy + i) * 100 + k4];
      a_s[i][0] = t4.x; a_s[i][1] = t4.y; a_s[i][2] = t4.z; a_s[i][3] = t4.w;
    }
#pragma unroll
    for (int kk = 0; kk < 4; ++kk) {
      float4 b0 = *(const float4*)&pr[(k4 + kk) * 64 + px8];
      float4 b1 = *(const float4*)&pr[(k4 + kk) * 64 + px8 + 4];
      float bb[8] = {b0.x, b0.y, b0.z, b0.w, b1.x, b1.y, b1.z, b1.w};
#pragma unroll
      for (int i = 0; i < 6; ++i) {
        float a = a_s[i][kk];
#pragma unroll
        for (int j = 0; j < 8; ++j) acc[i][j] += a * bb[j];
      }
    }
  }

#pragma unroll
  for (int i = 0; i < 6; ++i) {
    int o = oy + i;
#pragma unroll
    for (int j = 0; j < 8; ++j) {
      int p = pb * 64 + px8 + j;
      int y = p / W_;
      int xx = p - y * W_;
      int y2 = y + 4; if (y2 >= H_) y2 -= H_;
      int x2 = xx + 4; if (x2 >= W_) x2 -= W_;
      out[o * HW_ + y2 * W_ + x2] = acc[i][j];
    }
  }
}

extern "C" void kernel_launch(void* const* d_in, const int* in_sizes, int n_in,
                              void* d_out, int out_size, void* d_ws, size_t ws_size,
                              hipStream_t stream) {
  (void)in_sizes; (void)n_in; (void)out_size; (void)ws_size;
  const float* x = (const float*)d_in[0];
  const float* temp = (const float*)d_in[1];
  const float* qkvw = (const float*)d_in[2];
  const float* dww = (const float*)d_in[3];
  const float* projw = (const float*)d_in[4];
  float* out = (float*)d_out;

  char* ws = (char*)d_ws;
  __hip_bfloat16* qkv = (__hip_bfloat16*)ws;                    // 288*69696*2 = 40,144,896 B
  __hip_bfloat16* qkvd = (__hip_bfloat16*)(ws + 40144896);      // 40,144,896 B
  float* tout = (float*)ws;                                      // reuse region A: 25*96*4096*4 = 39,321,600 B

  k_qkv<<<dim3(1089, 3), 128, 0, stream>>>(x, qkvw, qkv);
  k_dw<<<dim3((HW_ / 4 + 255) / 256, 288), 256, 0, stream>>>(qkv, dww, qkvd);
  k_attn<<<dim3(64, 25, 3), 64, 0, stream>>>(qkvd, temp, tout);
  k_merge<<<dim3(1089), 128, 0, stream>>>(tout, projw, out);
}

// Round 2
// 270.747 us; speedup vs baseline: 1.5828x; 1.5828x over previous
//
#include <hip/hip_runtime.h>
#include <hip/hip_bf16.h>

#define HW_ 69696
#define W_ 264
#define H_ 264

typedef short bf16x8 __attribute__((ext_vector_type(8)));
typedef float f32x4 __attribute__((ext_vector_type(4)));

static __device__ __forceinline__ unsigned short f2b(float f) {
  __hip_bfloat16 h = __float2bfloat16(f);
  return *reinterpret_cast<unsigned short*>(&h);
}
static __device__ __forceinline__ float b2f(unsigned short u) {
  __hip_bfloat16 h;
  *reinterpret_cast<unsigned short*>(&h) = u;
  return __bfloat162float(h);
}

// ---------------- k_pre: roll(-4,-4) + f32->bf16 + transpose -> xbT[px][96] ----------------
__global__ __launch_bounds__(256) void k_pre(const float* __restrict__ x,
                                             unsigned short* __restrict__ xbT) {
  __shared__ unsigned short t_[96 * 70];  // [c][px], pitch 70 (conflict-free transpose read)
  __shared__ int rp[64];
  const int tid = threadIdx.x;
  const int px0 = blockIdx.x * 64;
  if (tid < 64) {
    int p = px0 + tid;
    int y = p / W_, xx = p - y * W_;
    int y2 = y + 4; if (y2 >= H_) y2 -= H_;
    int x2 = xx + 4; if (x2 >= W_) x2 -= W_;
    rp[tid] = y2 * W_ + x2;
  }
  __syncthreads();
  for (int l = tid; l < 96 * 64; l += 256) {
    int c = l >> 6, j = l & 63;
    t_[c * 70 + j] = f2b(x[c * HW_ + rp[j]]);
  }
  __syncthreads();
  const int pxl = tid >> 2, qp = tid & 3;
  unsigned int tmp[12];
#pragma unroll
  for (int i = 0; i < 12; ++i) {
    unsigned int lo = t_[(qp * 24 + 2 * i) * 70 + pxl];
    unsigned int hi = t_[(qp * 24 + 2 * i + 1) * 70 + pxl];
    tmp[i] = lo | (hi << 16);
  }
  uint4* dst = (uint4*)(xbT + (size_t)(px0 + pxl) * 96 + qp * 24);
  dst[0] = make_uint4(tmp[0], tmp[1], tmp[2], tmp[3]);
  dst[1] = make_uint4(tmp[4], tmp[5], tmp[6], tmp[7]);
  dst[2] = make_uint4(tmp[8], tmp[9], tmp[10], tmp[11]);
}

// ---------------- k_gemm: C[96][HW] = W(96x96) @ X(96xHW) via MFMA bf16 ----------------
// bT is X^T [HW][96] bf16. mode 0: bf16 out (qkv chunk oc). mode 1: f32 out + roll(+4).
__global__ __launch_bounds__(256, 2) void k_gemm(const float* __restrict__ w,
                                                 const unsigned short* __restrict__ bT,
                                                 unsigned short* __restrict__ outb,
                                                 float* __restrict__ outf,
                                                 int mode) {
  __shared__ __align__(16) char smem[46592];
  unsigned short* As = (unsigned short*)smem;   // [96][104]
  unsigned short* Bs = As + 96 * 104;           // [128][104]
  unsigned short* Cs = (unsigned short*)smem;   // epilogue overlay [96][136]

  const int tid = threadIdx.x;
  const int px0 = blockIdx.x * 128;
  const int oc = blockIdx.y;
  const int npx = min(128, HW_ - px0);

  // stage A: 96x96 f32 -> bf16, pitch 104
  const float* wp = w + oc * 96 * 96;
  for (int l = tid; l < 96 * 24; l += 256) {
    int o = l / 24, c4 = (l - (l / 24) * 24) * 4;
    float4 v = *(const float4*)&wp[o * 96 + c4];
    unsigned int p0 = (unsigned int)f2b(v.x) | ((unsigned int)f2b(v.y) << 16);
    unsigned int p1 = (unsigned int)f2b(v.z) | ((unsigned int)f2b(v.w) << 16);
    *(uint2*)&As[o * 104 + c4] = make_uint2(p0, p1);
  }
  // stage B: contiguous 192 B/row from bT, pitch 104
  {
    const int nbytes = npx * 192;
    const char* src = (const char*)(bT + (size_t)px0 * 96);
    for (int off = tid * 16; off < nbytes; off += 256 * 16) {
      uint4 v = *(const uint4*)(src + off);
      int row = off / 192;
      int colb = off - row * 192;
      *(uint4*)((char*)Bs + row * 208 + colb) = v;
    }
  }
  __syncthreads();

  const int wid = tid >> 6, lane = tid & 63;
  const int quad = lane >> 4, lo = lane & 15;
  f32x4 acc[6][2];
#pragma unroll
  for (int mt = 0; mt < 6; ++mt)
#pragma unroll
    for (int nt = 0; nt < 2; ++nt) acc[mt][nt] = {0.f, 0.f, 0.f, 0.f};

#pragma unroll
  for (int ks = 0; ks < 3; ++ks) {
    const int kb = ks * 32 + quad * 8;
    bf16x8 b[2];
#pragma unroll
    for (int nt = 0; nt < 2; ++nt)
      b[nt] = *(const bf16x8*)&Bs[(wid * 32 + nt * 16 + lo) * 104 + kb];
#pragma unroll
    for (int mt = 0; mt < 6; ++mt) {
      bf16x8 a = *(const bf16x8*)&As[(mt * 16 + lo) * 104 + kb];
#pragma unroll
      for (int nt = 0; nt < 2; ++nt)
        acc[mt][nt] = __builtin_amdgcn_mfma_f32_16x16x32_bf16(a, b[nt], acc[mt][nt], 0, 0, 0);
    }
  }

  if (mode == 0) {
    __syncthreads();  // all LDS reads done before overlay
#pragma unroll
    for (int mt = 0; mt < 6; ++mt)
#pragma unroll
      for (int nt = 0; nt < 2; ++nt)
#pragma unroll
        for (int r = 0; r < 4; ++r)
          Cs[(mt * 16 + quad * 4 + r) * 136 + wid * 32 + nt * 16 + lo] = f2b(acc[mt][nt][r]);
    __syncthreads();
    for (int c = tid; c < 96 * 16; c += 256) {
      int row = c >> 4, part = c & 15;
      if (part * 8 < npx) {
        uint4 v = *(const uint4*)&Cs[row * 136 + part * 8];
        *(uint4*)(outb + (size_t)(oc * 96 + row) * HW_ + px0 + part * 8) = v;
      }
    }
  } else {
#pragma unroll
    for (int nt = 0; nt < 2; ++nt) {
      int px = px0 + wid * 32 + nt * 16 + lo;
      if (px < HW_) {
        int y = px / W_, xx = px - y * W_;
        int y2 = y + 4; if (y2 >= H_) y2 -= H_;
        int x2 = xx + 4; if (x2 >= W_) x2 -= W_;
        int tp = y2 * W_ + x2;
#pragma unroll
        for (int mt = 0; mt < 6; ++mt) {
          int row = mt * 16 + quad * 4;
#pragma unroll
          for (int r = 0; r < 4; ++r)
            outf[(size_t)(row + r) * HW_ + tp] = acc[mt][nt][r];
        }
      }
    }
  }
}

// ---------------- k_dw: 3x3 depthwise conv, 8 px/thread, bf16 ----------------
__global__ __launch_bounds__(256) void k_dw(const unsigned short* __restrict__ qkv,
                                            const float* __restrict__ dw,
                                            unsigned short* __restrict__ out) {
  const int ch = blockIdx.y;
  const int g = blockIdx.x * 256 + threadIdx.x;
  if (g >= HW_ / 8) return;
  const int p0 = g * 8;
  const int y = p0 / W_;
  const int x0 = p0 - y * W_;  // multiple of 8, rows are 264 = 33*8 so no row crossing
  const float* wk = dw + ch * 9;
  float wv[9];
#pragma unroll
  for (int q = 0; q < 9; ++q) wv[q] = wk[q];
  const unsigned short* src = qkv + (size_t)ch * HW_;
  float a[8] = {0.f, 0.f, 0.f, 0.f, 0.f, 0.f, 0.f, 0.f};
#pragma unroll
  for (int dy = 0; dy < 3; ++dy) {
    int yy = y + dy - 1;
    if ((unsigned)yy < (unsigned)H_) {
      const unsigned short* row = src + yy * W_ + x0;
      float v[10];
      v[0] = (x0 > 0) ? b2f(row[-1]) : 0.f;
      ushort4 m0 = *(const ushort4*)(row);
      ushort4 m1 = *(const ushort4*)(row + 4);
      v[1] = b2f(m0.x); v[2] = b2f(m0.y); v[3] = b2f(m0.z); v[4] = b2f(m0.w);
      v[5] = b2f(m1.x); v[6] = b2f(m1.y); v[7] = b2f(m1.z); v[8] = b2f(m1.w);
      v[9] = (x0 + 8 < W_) ? b2f(row[8]) : 0.f;
      float w0 = wv[dy * 3], w1 = wv[dy * 3 + 1], w2 = wv[dy * 3 + 2];
#pragma unroll
      for (int j = 0; j < 8; ++j) a[j] += w0 * v[j] + w1 * v[j + 1] + w2 * v[j + 2];
    }
  }
  unsigned short* dst = out + (size_t)ch * HW_ + p0;
  ushort4 s0 = make_ushort4(f2b(a[0]), f2b(a[1]), f2b(a[2]), f2b(a[3]));
  ushort4 s1 = make_ushort4(f2b(a[4]), f2b(a[5]), f2b(a[6]), f2b(a[7]));
  *(ushort4*)(dst) = s0;
  *(ushort4*)(dst + 4) = s1;
}

// ---------------- k_attn: windowed channel attention (unchanged from R1) ----------------
__global__ __launch_bounds__(64) void k_attn(const __hip_bfloat16* __restrict__ qd,
                                             const float* __restrict__ temp,
                                             float* __restrict__ tout) {
  __shared__ __align__(16) float qk[2 * 64 * 36];
  __shared__ __align__(16) float vsm[32 * 68];
  __shared__ __align__(16) float att[32 * 36];
  __shared__ float invn[64];
  const int tid = threadIdx.x;
  const int wi = blockIdx.x;
  const int t = blockIdx.y;
  const int h = blockIdx.z;
  const int i0 = (t / 5) * 50, j0 = (t % 5) * 50;
  const int wy = wi >> 3, wx = wi & 7;
  const int gy = i0 + wy * 8 + (tid >> 3);
  const int gx = j0 + wx * 8 + (tid & 7);
  const int gp = gy * W_ + gx;
  const int cb = h * 32;
  float* qsT = qk;
  float* ksT = qk + 64 * 36;

#pragma unroll 4
  for (int c = 0; c < 32; ++c) {
    qsT[tid * 36 + c] = __bfloat162float(qd[(cb + c) * HW_ + gp]);
    ksT[tid * 36 + c] = __bfloat162float(qd[(96 + cb + c) * HW_ + gp]);
    vsm[c * 68 + tid] = __bfloat162float(qd[(192 + cb + c) * HW_ + gp]);
  }
  __syncthreads();

  {
    const float* bp = (tid < 32) ? qsT : ksT;
    const int r = tid & 31;
    float ss = 0.f;
    for (int m = 0; m < 64; ++m) {
      float v = bp[m * 36 + r];
      ss += v * v;
    }
    invn[tid] = 1.f / fmaxf(sqrtf(ss), 1e-12f);
  }
  __syncthreads();

  const float tscale = temp[h];
  {
    const int c4 = (tid & 7) * 4;
    const int d4 = (tid >> 3) * 4;
    float acc[4][4] = {};
    for (int m = 0; m < 64; ++m) {
      float4 qv = *(const float4*)&qsT[m * 36 + c4];
      float4 kv = *(const float4*)&ksT[m * 36 + d4];
      float qa[4] = {qv.x, qv.y, qv.z, qv.w};
      float ka[4] = {kv.x, kv.y, kv.z, kv.w};
#pragma unroll
      for (int i = 0; i < 4; ++i)
#pragma unroll
        for (int j = 0; j < 4; ++j) acc[i][j] += qa[i] * ka[j];
    }
#pragma unroll
    for (int i = 0; i < 4; ++i) {
      float iq = invn[c4 + i];
      float4 w4;
      w4.x = fmaxf(acc[i][0] * iq * invn[32 + d4 + 0] * tscale, 0.f);
      w4.y = fmaxf(acc[i][1] * iq * invn[32 + d4 + 1] * tscale, 0.f);
      w4.z = fmaxf(acc[i][2] * iq * invn[32 + d4 + 2] * tscale, 0.f);
      w4.w = fmaxf(acc[i][3] * iq * invn[32 + d4 + 3] * tscale, 0.f);
      *(float4*)&att[(c4 + i) * 36 + d4] = w4;
    }
  }
  __syncthreads();

  {
    const int n4 = (tid & 15) * 4;
    const int cg0 = (tid >> 4) * 4;
    float acc[2][4][4] = {};
    for (int db = 0; db < 8; ++db) {
      float4 vr[4];
#pragma unroll
      for (int r = 0; r < 4; ++r) vr[r] = *(const float4*)&vsm[(db * 4 + r) * 68 + n4];
#pragma unroll
      for (int gci = 0; gci < 2; ++gci) {
        int cbase = cg0 + gci * 16;
#pragma unroll
        for (int i = 0; i < 4; ++i) {
          float4 a4 = *(const float4*)&att[(cbase + i) * 36 + db * 4];
          float aa[4] = {a4.x, a4.y, a4.z, a4.w};
#pragma unroll
          for (int r = 0; r < 4; ++r) {
            acc[gci][i][0] += aa[r] * vr[r].x;
            acc[gci][i][1] += aa[r] * vr[r].y;
            acc[gci][i][2] += aa[r] * vr[r].z;
            acc[gci][i][3] += aa[r] * vr[r].w;
          }
        }
      }
    }
    const int ly = wy * 8 + (n4 >> 3);
    const int lx = wx * 8 + (n4 & 7);
    const int sp = ly * 64 + lx;
#pragma unroll
    for (int gci = 0; gci < 2; ++gci)
#pragma unroll
      for (int i = 0; i < 4; ++i) {
        int c = cb + cg0 + gci * 16 + i;
        float4 o4 = make_float4(acc[gci][i][0], acc[gci][i][1], acc[gci][i][2], acc[gci][i][3]);
        *(float4*)&tout[(t * 96 + c) * 4096 + sp] = o4;
      }
  }
}

// ---------------- k_avg: overlap-average -> predsT[px][96] bf16 ----------------
__global__ __launch_bounds__(256) void k_avg(const float* __restrict__ tout,
                                             unsigned short* __restrict__ predsT) {
  __shared__ unsigned short t_[96 * 70];
  const int tid = threadIdx.x;
  const int px0 = blockIdx.x * 64;
  for (int l = tid; l < 96 * 64; l += 256) {
    int c = l >> 6, j = l & 63;
    int p = px0 + j;
    int y = p / W_, xx = p - y * W_;
    int loy = (y >= 64) ? (y - 14) / 50 : 0;
    int hiy = y / 50; if (hiy > 4) hiy = 4;
    int lox = (xx >= 64) ? (xx - 14) / 50 : 0;
    int hix = xx / 50; if (hix > 4) hix = 4;
    float s = 0.f;
    int cnt = 0;
    for (int ty = loy; ty <= hiy; ++ty)
      for (int tx = lox; tx <= hix; ++tx) {
        s += tout[((ty * 5 + tx) * 96 + c) * 4096 + ((y - ty * 50) << 6) + (xx - tx * 50)];
        ++cnt;
      }
    t_[c * 70 + j] = f2b(s / (float)cnt);
  }
  __syncthreads();
  const int pxl = tid >> 2, qp = tid & 3;
  unsigned int tmp[12];
#pragma unroll
  for (int i = 0; i < 12; ++i) {
    unsigned int lo = t_[(qp * 24 + 2 * i) * 70 + pxl];
    unsigned int hi = t_[(qp * 24 + 2 * i + 1) * 70 + pxl];
    tmp[i] = lo | (hi << 16);
  }
  uint4* dst = (uint4*)(predsT + (size_t)(px0 + pxl) * 96 + qp * 24);
  dst[0] = make_uint4(tmp[0], tmp[1], tmp[2], tmp[3]);
  dst[1] = make_uint4(tmp[4], tmp[5], tmp[6], tmp[7]);
  dst[2] = make_uint4(tmp[8], tmp[9], tmp[10], tmp[11]);
}

extern "C" void kernel_launch(void* const* d_in, const int* in_sizes, int n_in,
                              void* d_out, int out_size, void* d_ws, size_t ws_size,
                              hipStream_t stream) {
  (void)in_sizes; (void)n_in; (void)out_size; (void)ws_size;
  const float* x = (const float*)d_in[0];
  const float* temp = (const float*)d_in[1];
  const float* qkvw = (const float*)d_in[2];
  const float* dww = (const float*)d_in[3];
  const float* projw = (const float*)d_in[4];
  float* out = (float*)d_out;

  char* ws = (char*)d_ws;
  const size_t SZQ = (size_t)288 * HW_ * 2;  // 40,144,896 B
  // R0 [0, SZQ): qkv (bf16) -> later tout (f32, 39.3 MB)
  // R1 [SZQ, 2*SZQ): xbT (13.4 MB) -> qkvd (bf16) -> predsT (13.4 MB)
  unsigned short* qkvb = (unsigned short*)ws;
  float* tout = (float*)ws;
  unsigned short* xbT = (unsigned short*)(ws + SZQ);
  unsigned short* qkvd = (unsigned short*)(ws + SZQ);
  unsigned short* predsT = (unsigned short*)(ws + SZQ);

  k_pre<<<dim3(1089), 256, 0, stream>>>(x, xbT);
  k_gemm<<<dim3(545, 3), 256, 0, stream>>>(qkvw, xbT, qkvb, nullptr, 0);
  k_dw<<<dim3(35, 288), 256, 0, stream>>>(qkvb, dww, qkvd);
  k_attn<<<dim3(64, 25, 3), 64, 0, stream>>>((const __hip_bfloat16*)qkvd, temp, tout);
  k_avg<<<dim3(1089), 256, 0, stream>>>(tout, predsT);
  k_gemm<<<dim3(545, 1), 256, 0, stream>>>(projw, predsT, nullptr, out, 1);
}

// Round 3
// 253.198 us; speedup vs baseline: 1.6925x; 1.0693x over previous
//
#include <hip/hip_runtime.h>
#include <hip/hip_bf16.h>

#define HW_ 69696
#define W_ 264
#define H_ 264

typedef short bf16x8 __attribute__((ext_vector_type(8)));
typedef float f32x4 __attribute__((ext_vector_type(4)));

static __device__ __forceinline__ unsigned short f2b(float f) {
  __hip_bfloat16 h = __float2bfloat16(f);
  return *reinterpret_cast<unsigned short*>(&h);
}
static __device__ __forceinline__ float b2f(unsigned short u) {
  __hip_bfloat16 h;
  *reinterpret_cast<unsigned short*>(&h) = u;
  return __bfloat162float(h);
}

// ---------------- k_pre: roll(-4,-4) + f32->bf16 + transpose -> xbT[px][96] ----------------
__global__ __launch_bounds__(256) void k_pre(const float* __restrict__ x,
                                             unsigned short* __restrict__ xbT) {
  __shared__ unsigned short t_[96 * 70];
  __shared__ int rp[64];
  const int tid = threadIdx.x;
  const int px0 = blockIdx.x * 64;
  if (tid < 64) {
    int p = px0 + tid;
    int y = p / W_, xx = p - y * W_;
    int y2 = y + 4; if (y2 >= H_) y2 -= H_;
    int x2 = xx + 4; if (x2 >= W_) x2 -= W_;
    rp[tid] = y2 * W_ + x2;
  }
  __syncthreads();
  for (int l = tid; l < 96 * 64; l += 256) {
    int c = l >> 6, j = l & 63;
    t_[c * 70 + j] = f2b(x[c * HW_ + rp[j]]);
  }
  __syncthreads();
  const int pxl = tid >> 2, qp = tid & 3;
  unsigned int tmp[12];
#pragma unroll
  for (int i = 0; i < 12; ++i) {
    unsigned int lo = t_[(qp * 24 + 2 * i) * 70 + pxl];
    unsigned int hi = t_[(qp * 24 + 2 * i + 1) * 70 + pxl];
    tmp[i] = lo | (hi << 16);
  }
  uint4* dst = (uint4*)(xbT + (size_t)(px0 + pxl) * 96 + qp * 24);
  dst[0] = make_uint4(tmp[0], tmp[1], tmp[2], tmp[3]);
  dst[1] = make_uint4(tmp[4], tmp[5], tmp[6], tmp[7]);
  dst[2] = make_uint4(tmp[8], tmp[9], tmp[10], tmp[11]);
}

// ---------------- k_gemm: C = W(96x96) @ X(96xHW), MFMA bf16 ----------------
// bT: [px][96] bf16 records. mode 0: write records outb[px][288] at ch-offset oc*96.
// mode 1: f32 [c][HW] out + roll(+4).
__global__ __launch_bounds__(256, 2) void k_gemm(const float* __restrict__ w,
                                                 const unsigned short* __restrict__ bT,
                                                 unsigned short* __restrict__ outb,
                                                 float* __restrict__ outf,
                                                 int mode) {
  __shared__ __align__(16) char smem[46592];
  unsigned short* As = (unsigned short*)smem;   // [96][104]
  unsigned short* Bs = As + 96 * 104;           // [128][104]

  const int tid = threadIdx.x;
  const int px0 = blockIdx.x * 128;
  const int oc = blockIdx.y;
  const int npx = min(128, HW_ - px0);

  const float* wp = w + oc * 96 * 96;
  for (int l = tid; l < 96 * 24; l += 256) {
    int o = l / 24, c4 = (l - (l / 24) * 24) * 4;
    float4 v = *(const float4*)&wp[o * 96 + c4];
    unsigned int p0 = (unsigned int)f2b(v.x) | ((unsigned int)f2b(v.y) << 16);
    unsigned int p1 = (unsigned int)f2b(v.z) | ((unsigned int)f2b(v.w) << 16);
    *(uint2*)&As[o * 104 + c4] = make_uint2(p0, p1);
  }
  {
    const int nbytes = npx * 192;
    const char* src = (const char*)(bT + (size_t)px0 * 96);
    for (int off = tid * 16; off < nbytes; off += 256 * 16) {
      uint4 v = *(const uint4*)(src + off);
      int row = off / 192;
      int colb = off - row * 192;
      *(uint4*)((char*)Bs + row * 208 + colb) = v;
    }
  }
  __syncthreads();

  const int wid = tid >> 6, lane = tid & 63;
  const int quad = lane >> 4, lo = lane & 15;
  f32x4 acc[6][2];
#pragma unroll
  for (int mt = 0; mt < 6; ++mt)
#pragma unroll
    for (int nt = 0; nt < 2; ++nt) acc[mt][nt] = {0.f, 0.f, 0.f, 0.f};

#pragma unroll
  for (int ks = 0; ks < 3; ++ks) {
    const int kb = ks * 32 + quad * 8;
    bf16x8 b[2];
#pragma unroll
    for (int nt = 0; nt < 2; ++nt)
      b[nt] = *(const bf16x8*)&Bs[(wid * 32 + nt * 16 + lo) * 104 + kb];
#pragma unroll
    for (int mt = 0; mt < 6; ++mt) {
      bf16x8 a = *(const bf16x8*)&As[(mt * 16 + lo) * 104 + kb];
#pragma unroll
      for (int nt = 0; nt < 2; ++nt)
        acc[mt][nt] = __builtin_amdgcn_mfma_f32_16x16x32_bf16(a, b[nt], acc[mt][nt], 0, 0, 0);
    }
  }

  if (mode == 0) {
    __syncthreads();
    unsigned short* Cs2 = (unsigned short*)smem;  // [128][104] px-major
#pragma unroll
    for (int mt = 0; mt < 6; ++mt)
#pragma unroll
      for (int nt = 0; nt < 2; ++nt) {
        int px_l = wid * 32 + nt * 16 + lo;
#pragma unroll
        for (int r = 0; r < 4; ++r)
          Cs2[px_l * 104 + mt * 16 + quad * 4 + r] = f2b(acc[mt][nt][r]);
      }
    __syncthreads();
    for (int i = tid; i < 128 * 12; i += 256) {
      int px_l = i / 12, u = i - (i / 12) * 12;
      if (px0 + px_l < HW_)
        *((uint4*)(outb + (size_t)(px0 + px_l) * 288 + oc * 96) + u) =
            ((const uint4*)(Cs2 + px_l * 104))[u];
    }
  } else {
#pragma unroll
    for (int nt = 0; nt < 2; ++nt) {
      int px = px0 + wid * 32 + nt * 16 + lo;
      if (px < HW_) {
        int y = px / W_, xx = px - y * W_;
        int y2 = y + 4; if (y2 >= H_) y2 -= H_;
        int x2 = xx + 4; if (x2 >= W_) x2 -= W_;
        int tp = y2 * W_ + x2;
#pragma unroll
        for (int mt = 0; mt < 6; ++mt) {
          int row = mt * 16 + quad * 4;
#pragma unroll
          for (int r = 0; r < 4; ++r)
            outf[(size_t)(row + r) * HW_ + tp] = acc[mt][nt][r];
        }
      }
    }
  }
}

// ---------------- k_dw: 3x3 depthwise conv on [px][288] records ----------------
// block: one image row y, px segment of 66, channel third (96 ch). LDS-staged.
__global__ __launch_bounds__(256) void k_dw(const unsigned short* __restrict__ qkv,
                                            const float* __restrict__ dw,
                                            unsigned short* __restrict__ out) {
  __shared__ __align__(16) unsigned short inS[3 * 68 * 96];  // [row][px-1..+66][96]
  __shared__ float dwS[96 * 9];
  __shared__ __align__(16) unsigned short outS[66 * 96];
  const int tid = threadIdx.x;
  const int y = blockIdx.x >> 2;
  const int px0 = (blockIdx.x & 3) * 66;
  const int part = blockIdx.y;  // 0..2 -> q/k/v 96-ch chunk

  for (int l = tid; l < 864; l += 256) dwS[l] = dw[part * 864 + l];
  for (int idx = tid; idx < 3 * 68 * 12; idx += 256) {
    int rec = idx / 12, u = idx - (idx / 12) * 12;
    int rr = rec / 68, pp = rec - rr * 68;
    int yy = y + rr - 1;
    int xg = px0 - 1 + pp;
    uint4 v = make_uint4(0u, 0u, 0u, 0u);
    if ((unsigned)yy < (unsigned)H_ && (unsigned)xg < (unsigned)W_)
      v = *((const uint4*)(qkv + ((size_t)yy * W_ + xg) * 288 + part * 96) + u);
    ((uint4*)inS)[rec * 12 + u] = v;
  }
  __syncthreads();

  for (int l = tid; l < 96 * 66; l += 256) {
    int c = l % 96, pxl = l / 96;
    float a = 0.f;
#pragma unroll
    for (int rr = 0; rr < 3; ++rr)
#pragma unroll
      for (int dx = 0; dx < 3; ++dx)
        a += dwS[c * 9 + rr * 3 + dx] * b2f(inS[(rr * 68 + pxl + dx) * 96 + c]);
    outS[pxl * 96 + c] = f2b(a);
  }
  __syncthreads();

  for (int idx = tid; idx < 66 * 12; idx += 256) {
    int rec = idx / 12, u = idx - (idx / 12) * 12;
    size_t pxg = (size_t)y * W_ + px0 + rec;
    *((uint4*)(out + pxg * 288 + part * 96) + u) = ((const uint4*)(outS + rec * 96))[u];
  }
}

// ---------------- k_attn: MFMA windowed channel attention ----------------
// block = (window wi, tile t), 192 thr = 3 waves, wave h = head h.
// qd: [px][288] bf16 records. tout: [t][96][64*64] bf16 (tile-image layout).
__global__ __launch_bounds__(192) void k_attn(const unsigned short* __restrict__ qd,
                                              const float* __restrict__ temp,
                                              unsigned short* __restrict__ tout) {
  __shared__ __align__(16) unsigned short flat[8 * 2320];   // 8 row-chunks, padded
  __shared__ __align__(16) unsigned short attnL[3 * 32 * 40];
  __shared__ float invn[3 * 32];
  const int tid = threadIdx.x;
  const int wi = blockIdx.x, t = blockIdx.y;
  const int i0 = (t / 5) * 50, j0 = (t % 5) * 50;
  const int wy = wi >> 3, wx = wi & 7;
  const int gy0 = i0 + wy * 8, gx0 = j0 + wx * 8;

  {  // stage: 8 chunks x 4608 B, fully coalesced
    const unsigned short* base = qd + ((size_t)gy0 * W_ + gx0) * 288;
    for (int idx = tid; idx < 8 * 288; idx += 192) {
      int r = idx / 288, u = idx - r * 288;
      uint4 v = *((const uint4*)(base + (size_t)r * (W_ * 288)) + u);
      *((uint4*)flat + r * 290 + u) = v;
    }
  }
  __syncthreads();

  const int h = tid >> 6, lane = tid & 63;
  const int quad = lane >> 4, lo = lane & 15;
  const int cb = h * 32;

  // gather q,k fragments: A[m=ch][k=px], B[k=px][n=ch]
  bf16x8 qf[2][2], kf[2][2];
#pragma unroll
  for (int mt = 0; mt < 2; ++mt)
#pragma unroll
    for (int kt = 0; kt < 2; ++kt) {
      const int rbase = (kt * 4 + quad) * 2320;
      const int cq = cb + mt * 16 + lo;
      const int ck = 96 + cb + mt * 16 + lo;
      bf16x8 q8, k8;
#pragma unroll
      for (int j = 0; j < 8; ++j) {
        q8[j] = (short)flat[rbase + j * 288 + cq];
        k8[j] = (short)flat[rbase + j * 288 + ck];
      }
      qf[mt][kt] = q8;
      kf[mt][kt] = k8;
    }

  // S = q k^T (raw), f32 acc
  f32x4 S[2][2];
#pragma unroll
  for (int mt = 0; mt < 2; ++mt)
#pragma unroll
    for (int nt = 0; nt < 2; ++nt) {
      S[mt][nt] = {0.f, 0.f, 0.f, 0.f};
#pragma unroll
      for (int kt = 0; kt < 2; ++kt)
        S[mt][nt] = __builtin_amdgcn_mfma_f32_16x16x32_bf16(qf[mt][kt], kf[nt][kt], S[mt][nt], 0, 0, 0);
    }

  // L2 norms from in-register fragments (16 px per lane), shfl-reduce across quads
  float ivk[2];
#pragma unroll
  for (int mt = 0; mt < 2; ++mt) {
    float sq = 0.f, sk = 0.f;
#pragma unroll
    for (int kt = 0; kt < 2; ++kt)
#pragma unroll
      for (int j = 0; j < 8; ++j) {
        float a = b2f((unsigned short)qf[mt][kt][j]);
        float b = b2f((unsigned short)kf[mt][kt][j]);
        sq += a * a;
        sk += b * b;
      }
    sq += __shfl_xor(sq, 16);
    sq += __shfl_xor(sq, 32);
    sk += __shfl_xor(sk, 16);
    sk += __shfl_xor(sk, 32);
    if (quad == 0) invn[h * 32 + mt * 16 + lo] = 1.f / fmaxf(sqrtf(sq), 1e-12f);
    ivk[mt] = 1.f / fmaxf(sqrtf(sk), 1e-12f);
  }
  __syncthreads();

  const float ts = temp[h];
#pragma unroll
  for (int mt = 0; mt < 2; ++mt)
#pragma unroll
    for (int nt = 0; nt < 2; ++nt)
#pragma unroll
      for (int r = 0; r < 4; ++r) {
        int c = mt * 16 + quad * 4 + r;
        float v = S[mt][nt][r] * invn[h * 32 + c] * ivk[nt] * ts;
        attnL[(h * 32 + c) * 40 + nt * 16 + lo] = f2b(fmaxf(v, 0.f));
      }
  __syncthreads();

  // out = attn @ v : A[m=c][k=d] from attnL (b128), B[k=d][n=px] from flat (contig ch, b128)
  bf16x8 af[2];
#pragma unroll
  for (int mt = 0; mt < 2; ++mt)
    af[mt] = *(const bf16x8*)&attnL[(h * 32 + mt * 16 + lo) * 40 + quad * 8];

  f32x4 O[2][4];
#pragma unroll
  for (int nt = 0; nt < 4; ++nt) {
    const int px = nt * 16 + lo;
    bf16x8 vf = *(const bf16x8*)&flat[(px >> 3) * 2320 + (px & 7) * 288 + 192 + cb + quad * 8];
#pragma unroll
    for (int mt = 0; mt < 2; ++mt) {
      if (nt == 0) O[mt][0] = {0.f, 0.f, 0.f, 0.f};
      f32x4 z = (nt == 0) ? O[mt][0] : f32x4{0.f, 0.f, 0.f, 0.f};
      O[mt][nt] = __builtin_amdgcn_mfma_f32_16x16x32_bf16(af[mt], vf, z, 0, 0, 0);
    }
  }

#pragma unroll
  for (int mt = 0; mt < 2; ++mt)
#pragma unroll
    for (int nt = 0; nt < 4; ++nt) {
      const int px = nt * 16 + lo;
      const int ly = wy * 8 + (px >> 3), lx = wx * 8 + (px & 7);
      const int sp = ly * 64 + lx;
#pragma unroll
      for (int r = 0; r < 4; ++r)
        tout[(size_t)(t * 96 + cb + mt * 16 + quad * 4 + r) * 4096 + sp] = f2b(O[mt][nt][r]);
    }
}

// ---------------- k_avg: overlap-average (bf16 tout) -> predsT[px][96] bf16 ----------------
__global__ __launch_bounds__(256) void k_avg(const unsigned short* __restrict__ tout,
                                             unsigned short* __restrict__ predsT) {
  __shared__ unsigned short t_[96 * 70];
  const int tid = threadIdx.x;
  const int px0 = blockIdx.x * 64;
  for (int l = tid; l < 96 * 64; l += 256) {
    int c = l >> 6, j = l & 63;
    int p = px0 + j;
    int y = p / W_, xx = p - y * W_;
    int loy = (y >= 64) ? (y - 14) / 50 : 0;
    int hiy = y / 50; if (hiy > 4) hiy = 4;
    int lox = (xx >= 64) ? (xx - 14) / 50 : 0;
    int hix = xx / 50; if (hix > 4) hix = 4;
    float s = 0.f;
    int cnt = 0;
    for (int ty = loy; ty <= hiy; ++ty)
      for (int tx = lox; tx <= hix; ++tx) {
        s += b2f(tout[(size_t)((ty * 5 + tx) * 96 + c) * 4096 + ((y - ty * 50) << 6) + (xx - tx * 50)]);
        ++cnt;
      }
    t_[c * 70 + j] = f2b(s / (float)cnt);
  }
  __syncthreads();
  const int pxl = tid >> 2, qp = tid & 3;
  unsigned int tmp[12];
#pragma unroll
  for (int i = 0; i < 12; ++i) {
    unsigned int lo = t_[(qp * 24 + 2 * i) * 70 + pxl];
    unsigned int hi = t_[(qp * 24 + 2 * i + 1) * 70 + pxl];
    tmp[i] = lo | (hi << 16);
  }
  uint4* dst = (uint4*)(predsT + (size_t)(px0 + pxl) * 96 + qp * 24);
  dst[0] = make_uint4(tmp[0], tmp[1], tmp[2], tmp[3]);
  dst[1] = make_uint4(tmp[4], tmp[5], tmp[6], tmp[7]);
  dst[2] = make_uint4(tmp[8], tmp[9], tmp[10], tmp[11]);
}

extern "C" void kernel_launch(void* const* d_in, const int* in_sizes, int n_in,
                              void* d_out, int out_size, void* d_ws, size_t ws_size,
                              hipStream_t stream) {
  (void)in_sizes; (void)n_in; (void)out_size; (void)ws_size;
  const float* x = (const float*)d_in[0];
  const float* temp = (const float*)d_in[1];
  const float* qkvw = (const float*)d_in[2];
  const float* dww = (const float*)d_in[3];
  const float* projw = (const float*)d_in[4];
  float* out = (float*)d_out;

  char* ws = (char*)d_ws;
  const size_t SZQ = (size_t)288 * HW_ * 2;  // 40,144,896 B
  // [0, SZQ):      qkvb [px][288]  -> later tout (19.7 MB, overlays after k_dw)
  // [SZQ, 2*SZQ):  xbT (13.4 MB) -> qkvd [px][288] -> predsT (13.4 MB)
  unsigned short* qkvb = (unsigned short*)ws;
  unsigned short* tout = (unsigned short*)ws;
  unsigned short* xbT = (unsigned short*)(ws + SZQ);
  unsigned short* qkvd = (unsigned short*)(ws + SZQ);
  unsigned short* predsT = (unsigned short*)(ws + SZQ);

  k_pre<<<dim3(1089), 256, 0, stream>>>(x, xbT);
  k_gemm<<<dim3(545, 3), 256, 0, stream>>>(qkvw, xbT, qkvb, nullptr, 0);
  k_dw<<<dim3(1056, 3), 256, 0, stream>>>(qkvb, dww, qkvd);
  k_attn<<<dim3(64, 25), 192, 0, stream>>>(qkvd, temp, tout);
  k_avg<<<dim3(1089), 256, 0, stream>>>(tout, predsT);
  k_gemm<<<dim3(545, 1), 256, 0, stream>>>(projw, predsT, nullptr, out, 1);
}

// Round 4
// 219.665 us; speedup vs baseline: 1.9508x; 1.1527x over previous
//
#include <hip/hip_runtime.h>
#include <hip/hip_bf16.h>

#define HW_ 69696
#define W_ 264
#define H_ 264

typedef short bf16x8 __attribute__((ext_vector_type(8)));
typedef float f32x4 __attribute__((ext_vector_type(4)));

static __device__ __forceinline__ unsigned short f2b(float f) {
  __hip_bfloat16 h = __float2bfloat16(f);
  return *reinterpret_cast<unsigned short*>(&h);
}
static __device__ __forceinline__ float b2f(unsigned short u) {
  __hip_bfloat16 h;
  *reinterpret_cast<unsigned short*>(&h) = u;
  return __bfloat162float(h);
}
static __device__ __forceinline__ float lo_f(unsigned int u) {
  union { unsigned int i; float f; } c; c.i = u << 16; return c.f;
}
static __device__ __forceinline__ float hi_f(unsigned int u) {
  union { unsigned int i; float f; } c; c.i = u & 0xffff0000u; return c.f;
}

// ---------------- k_pre: roll(-4,-4) + f32->bf16 + transpose -> xbT[px][96] ----------------
__global__ __launch_bounds__(256) void k_pre(const float* __restrict__ x,
                                             unsigned short* __restrict__ xbT) {
  __shared__ unsigned short t_[96 * 70];
  __shared__ int rp[64];
  const int tid = threadIdx.x;
  const int px0 = blockIdx.x * 64;
  if (tid < 64) {
    int p = px0 + tid;
    int y = p / W_, xx = p - y * W_;
    int y2 = y + 4; if (y2 >= H_) y2 -= H_;
    int x2 = xx + 4; if (x2 >= W_) x2 -= W_;
    rp[tid] = y2 * W_ + x2;
  }
  __syncthreads();
  for (int l = tid; l < 96 * 64; l += 256) {
    int c = l >> 6, j = l & 63;
    t_[c * 70 + j] = f2b(x[c * HW_ + rp[j]]);
  }
  __syncthreads();
  const int pxl = tid >> 2, qp = tid & 3;
  unsigned int tmp[12];
#pragma unroll
  for (int i = 0; i < 12; ++i) {
    unsigned int lo = t_[(qp * 24 + 2 * i) * 70 + pxl];
    unsigned int hi = t_[(qp * 24 + 2 * i + 1) * 70 + pxl];
    tmp[i] = lo | (hi << 16);
  }
  uint4* dst = (uint4*)(xbT + (size_t)(px0 + pxl) * 96 + qp * 24);
  dst[0] = make_uint4(tmp[0], tmp[1], tmp[2], tmp[3]);
  dst[1] = make_uint4(tmp[4], tmp[5], tmp[6], tmp[7]);
  dst[2] = make_uint4(tmp[8], tmp[9], tmp[10], tmp[11]);
}

// ---------------- k_gemm: C = W(96x96) @ X(96xHW), MFMA bf16 ----------------
// bT: [px][96] bf16 records. mode 0: write plane-8 layout outb[36][HW][8] (planes oc*12..+11).
// mode 1: f32 [c][HW] out + roll(+4).
__global__ __launch_bounds__(256, 3) void k_gemm(const float* __restrict__ w,
                                                 const unsigned short* __restrict__ bT,
                                                 unsigned short* __restrict__ outb,
                                                 float* __restrict__ outf,
                                                 int mode) {
  __shared__ __align__(16) char smem[46592];
  unsigned short* As = (unsigned short*)smem;   // [96][104]
  unsigned short* Bs = As + 96 * 104;           // [128][104]

  const int tid = threadIdx.x;
  const int px0 = blockIdx.x * 128;
  const int oc = blockIdx.y;
  const int npx = min(128, HW_ - px0);

  const float* wp = w + oc * 96 * 96;
  for (int l = tid; l < 96 * 24; l += 256) {
    int o = l / 24, c4 = (l - (l / 24) * 24) * 4;
    float4 v = *(const float4*)&wp[o * 96 + c4];
    unsigned int p0 = (unsigned int)f2b(v.x) | ((unsigned int)f2b(v.y) << 16);
    unsigned int p1 = (unsigned int)f2b(v.z) | ((unsigned int)f2b(v.w) << 16);
    *(uint2*)&As[o * 104 + c4] = make_uint2(p0, p1);
  }
  {
    const int nbytes = npx * 192;
    const char* src = (const char*)(bT + (size_t)px0 * 96);
    for (int off = tid * 16; off < nbytes; off += 256 * 16) {
      uint4 v = *(const uint4*)(src + off);
      int row = off / 192;
      int colb = off - row * 192;
      *(uint4*)((char*)Bs + row * 208 + colb) = v;
    }
  }
  __syncthreads();

  const int wid = tid >> 6, lane = tid & 63;
  const int quad = lane >> 4, lo = lane & 15;
  f32x4 acc[6][2];
#pragma unroll
  for (int mt = 0; mt < 6; ++mt)
#pragma unroll
    for (int nt = 0; nt < 2; ++nt) acc[mt][nt] = {0.f, 0.f, 0.f, 0.f};

#pragma unroll
  for (int ks = 0; ks < 3; ++ks) {
    const int kb = ks * 32 + quad * 8;
    bf16x8 b[2];
#pragma unroll
    for (int nt = 0; nt < 2; ++nt)
      b[nt] = *(const bf16x8*)&Bs[(wid * 32 + nt * 16 + lo) * 104 + kb];
#pragma unroll
    for (int mt = 0; mt < 6; ++mt) {
      bf16x8 a = *(const bf16x8*)&As[(mt * 16 + lo) * 104 + kb];
#pragma unroll
      for (int nt = 0; nt < 2; ++nt)
        acc[mt][nt] = __builtin_amdgcn_mfma_f32_16x16x32_bf16(a, b[nt], acc[mt][nt], 0, 0, 0);
    }
  }

  if (mode == 0) {
    __syncthreads();
    unsigned short* Cs2 = (unsigned short*)smem;  // [128][104] px-major
#pragma unroll
    for (int mt = 0; mt < 6; ++mt)
#pragma unroll
      for (int nt = 0; nt < 2; ++nt) {
        int px_l = wid * 32 + nt * 16 + lo;
#pragma unroll
        for (int r = 0; r < 4; ++r)
          Cs2[px_l * 104 + mt * 16 + quad * 4 + r] = f2b(acc[mt][nt][r]);
      }
    __syncthreads();
    for (int i = tid; i < 128 * 12; i += 256) {
      int pxl = i & 127, j = i >> 7;
      if (px0 + pxl < HW_)
        *((uint4*)outb + (size_t)(oc * 12 + j) * HW_ + px0 + pxl) =
            ((const uint4*)(Cs2 + pxl * 104))[j];
    }
  } else {
#pragma unroll
    for (int nt = 0; nt < 2; ++nt) {
      int px = px0 + wid * 32 + nt * 16 + lo;
      if (px < HW_) {
        int y = px / W_, xx = px - y * W_;
        int y2 = y + 4; if (y2 >= H_) y2 -= H_;
        int x2 = xx + 4; if (x2 >= W_) x2 -= W_;
        int tp = y2 * W_ + x2;
#pragma unroll
        for (int mt = 0; mt < 6; ++mt) {
          int row = mt * 16 + quad * 4;
#pragma unroll
          for (int r = 0; r < 4; ++r)
            outf[(size_t)(row + r) * HW_ + tp] = acc[mt][nt][r];
        }
      }
    }
  }
}

// ---------------- k_dw: 3x3 depthwise conv on plane-8 layout [36][HW][8] ----------------
// thread = (px, plane u). Direct coalesced global loads; weights are scalar (u uniform).
__global__ __launch_bounds__(256) void k_dw(const unsigned short* __restrict__ qkv,
                                            const float* __restrict__ dw,
                                            unsigned short* __restrict__ out) {
  const int u = blockIdx.y;  // 0..35
  const int px = blockIdx.x * 256 + threadIdx.x;
  if (px >= HW_) return;
  const int y = px / W_, x = px - y * W_;
  const uint4* plane = (const uint4*)qkv + (size_t)u * HW_;
  const float* wp = dw + u * 72;  // channels u*8..u*8+7, 9 taps each (uniform -> s_load)
  float wv[72];
#pragma unroll
  for (int i = 0; i < 72; ++i) wv[i] = wp[i];

  float acc[8] = {0.f, 0.f, 0.f, 0.f, 0.f, 0.f, 0.f, 0.f};
#pragma unroll
  for (int dy = 0; dy < 3; ++dy) {
    const int yy = y + dy - 1;
#pragma unroll
    for (int dx = 0; dx < 3; ++dx) {
      const int xx2 = x + dx - 1;
      const int t = dy * 3 + dx;
      uint4 v = make_uint4(0u, 0u, 0u, 0u);
      if ((unsigned)yy < (unsigned)H_ && (unsigned)xx2 < (unsigned)W_)
        v = plane[yy * W_ + xx2];
      float f[8];
      f[0] = lo_f(v.x); f[1] = hi_f(v.x);
      f[2] = lo_f(v.y); f[3] = hi_f(v.y);
      f[4] = lo_f(v.z); f[5] = hi_f(v.z);
      f[6] = lo_f(v.w); f[7] = hi_f(v.w);
#pragma unroll
      for (int ci = 0; ci < 8; ++ci) acc[ci] += wv[ci * 9 + t] * f[ci];
    }
  }
  uint4 o;
  o.x = (unsigned int)f2b(acc[0]) | ((unsigned int)f2b(acc[1]) << 16);
  o.y = (unsigned int)f2b(acc[2]) | ((unsigned int)f2b(acc[3]) << 16);
  o.z = (unsigned int)f2b(acc[4]) | ((unsigned int)f2b(acc[5]) << 16);
  o.w = (unsigned int)f2b(acc[6]) | ((unsigned int)f2b(acc[7]) << 16);
  *((uint4*)out + (size_t)u * HW_ + px) = o;
}

// ---------------- k_attn: MFMA windowed channel attention (plane-8 input) ----------------
// block = (window wi, tile t), 192 thr = 3 waves, wave h = head h.
// qd: [36][HW][8] bf16. tout: [t][96][64*64] bf16 (tile-image layout).
#define P1 296   // shorts per px in LDS   (37 uint4)
#define P8 2376  // shorts per row of 8 px (297 uint4)
__global__ __launch_bounds__(192) void k_attn(const unsigned short* __restrict__ qd,
                                              const float* __restrict__ temp,
                                              unsigned short* __restrict__ tout) {
  __shared__ __align__(16) unsigned short flat[8 * P8];
  __shared__ __align__(16) unsigned short attnL[3 * 32 * 40];
  __shared__ float invn[3 * 32];
  const int tid = threadIdx.x;
  const int wi = blockIdx.x, t = blockIdx.y;
  const int i0 = (t / 5) * 50, j0 = (t % 5) * 50;
  const int wy = wi >> 3, wx = wi & 7;
  const int gy0 = i0 + wy * 8, gx0 = j0 + wx * 8;

  {  // stage from planes: (u, r, j) -> flat[r][j][u*8]
    const size_t base = (size_t)gy0 * W_ + gx0;
    for (int idx = tid; idx < 36 * 64; idx += 192) {
      int u = idx >> 6, rj = idx & 63, r = rj >> 3, j = rj & 7;
      uint4 v = ((const uint4*)qd)[(size_t)u * HW_ + base + r * W_ + j];
      ((uint4*)flat)[r * 297 + j * 37 + u] = v;
    }
  }
  __syncthreads();

  const int h = tid >> 6, lane = tid & 63;
  const int quad = lane >> 4, lo = lane & 15;
  const int cb = h * 32;

  bf16x8 qf[2][2], kf[2][2];
#pragma unroll
  for (int mt = 0; mt < 2; ++mt)
#pragma unroll
    for (int kt = 0; kt < 2; ++kt) {
      const int rbase = (kt * 4 + quad) * P8;
      const int cq = cb + mt * 16 + lo;
      const int ck = 96 + cb + mt * 16 + lo;
      bf16x8 q8, k8;
#pragma unroll
      for (int j = 0; j < 8; ++j) {
        q8[j] = (short)flat[rbase + j * P1 + cq];
        k8[j] = (short)flat[rbase + j * P1 + ck];
      }
      qf[mt][kt] = q8;
      kf[mt][kt] = k8;
    }

  f32x4 S[2][2];
#pragma unroll
  for (int mt = 0; mt < 2; ++mt)
#pragma unroll
    for (int nt = 0; nt < 2; ++nt) {
      S[mt][nt] = {0.f, 0.f, 0.f, 0.f};
#pragma unroll
      for (int kt = 0; kt < 2; ++kt)
        S[mt][nt] = __builtin_amdgcn_mfma_f32_16x16x32_bf16(qf[mt][kt], kf[nt][kt], S[mt][nt], 0, 0, 0);
    }

  float ivk[2];
#pragma unroll
  for (int mt = 0; mt < 2; ++mt) {
    float sq = 0.f, sk = 0.f;
#pragma unroll
    for (int kt = 0; kt < 2; ++kt)
#pragma unroll
      for (int j = 0; j < 8; ++j) {
        float a = b2f((unsigned short)qf[mt][kt][j]);
        float b = b2f((unsigned short)kf[mt][kt][j]);
        sq += a * a;
        sk += b * b;
      }
    sq += __shfl_xor(sq, 16);
    sq += __shfl_xor(sq, 32);
    sk += __shfl_xor(sk, 16);
    sk += __shfl_xor(sk, 32);
    if (quad == 0) invn[h * 32 + mt * 16 + lo] = 1.f / fmaxf(sqrtf(sq), 1e-12f);
    ivk[mt] = 1.f / fmaxf(sqrtf(sk), 1e-12f);
  }
  __syncthreads();

  const float ts = temp[h];
#pragma unroll
  for (int mt = 0; mt < 2; ++mt)
#pragma unroll
    for (int nt = 0; nt < 2; ++nt)
#pragma unroll
      for (int r = 0; r < 4; ++r) {
        int c = mt * 16 + quad * 4 + r;
        float v = S[mt][nt][r] * invn[h * 32 + c] * ivk[nt] * ts;
        attnL[(h * 32 + c) * 40 + nt * 16 + lo] = f2b(fmaxf(v, 0.f));
      }
  __syncthreads();

  bf16x8 af[2];
#pragma unroll
  for (int mt = 0; mt < 2; ++mt)
    af[mt] = *(const bf16x8*)&attnL[(h * 32 + mt * 16 + lo) * 40 + quad * 8];

  f32x4 O[2][4];
#pragma unroll
  for (int nt = 0; nt < 4; ++nt) {
    const int px = nt * 16 + lo;
    bf16x8 vf = *(const bf16x8*)&flat[(px >> 3) * P8 + (px & 7) * P1 + 192 + cb + quad * 8];
#pragma unroll
    for (int mt = 0; mt < 2; ++mt) {
      f32x4 z = {0.f, 0.f, 0.f, 0.f};
      O[mt][nt] = __builtin_amdgcn_mfma_f32_16x16x32_bf16(af[mt], vf, z, 0, 0, 0);
    }
  }

#pragma unroll
  for (int mt = 0; mt < 2; ++mt)
#pragma unroll
    for (int nt = 0; nt < 4; ++nt) {
      const int px = nt * 16 + lo;
      const int ly = wy * 8 + (px >> 3), lx = wx * 8 + (px & 7);
      const int sp = ly * 64 + lx;
#pragma unroll
      for (int r = 0; r < 4; ++r)
        tout[(size_t)(t * 96 + cb + mt * 16 + quad * 4 + r) * 4096 + sp] = f2b(O[mt][nt][r]);
    }
}

// ---------------- k_avg: overlap-average (bf16 tout) -> predsT[px][96] bf16 ----------------
__global__ __launch_bounds__(256) void k_avg(const unsigned short* __restrict__ tout,
                                             unsigned short* __restrict__ predsT) {
  __shared__ unsigned short t_[96 * 70];
  const int tid = threadIdx.x;
  const int px0 = blockIdx.x * 64;
  for (int l = tid; l < 96 * 64; l += 256) {
    int c = l >> 6, j = l & 63;
    int p = px0 + j;
    int y = p / W_, xx = p - y * W_;
    int loy = (y >= 64) ? (y - 14) / 50 : 0;
    int hiy = y / 50; if (hiy > 4) hiy = 4;
    int lox = (xx >= 64) ? (xx - 14) / 50 : 0;
    int hix = xx / 50; if (hix > 4) hix = 4;
    float s = 0.f;
    int cnt = 0;
    for (int ty = loy; ty <= hiy; ++ty)
      for (int tx = lox; tx <= hix; ++tx) {
        s += b2f(tout[(size_t)((ty * 5 + tx) * 96 + c) * 4096 + ((y - ty * 50) << 6) + (xx - tx * 50)]);
        ++cnt;
      }
    t_[c * 70 + j] = f2b(s / (float)cnt);
  }
  __syncthreads();
  const int pxl = tid >> 2, qp = tid & 3;
  unsigned int tmp[12];
#pragma unroll
  for (int i = 0; i < 12; ++i) {
    unsigned int lo = t_[(qp * 24 + 2 * i) * 70 + pxl];
    unsigned int hi = t_[(qp * 24 + 2 * i + 1) * 70 + pxl];
    tmp[i] = lo | (hi << 16);
  }
  uint4* dst = (uint4*)(predsT + (size_t)(px0 + pxl) * 96 + qp * 24);
  dst[0] = make_uint4(tmp[0], tmp[1], tmp[2], tmp[3]);
  dst[1] = make_uint4(tmp[4], tmp[5], tmp[6], tmp[7]);
  dst[2] = make_uint4(tmp[8], tmp[9], tmp[10], tmp[11]);
}

extern "C" void kernel_launch(void* const* d_in, const int* in_sizes, int n_in,
                              void* d_out, int out_size, void* d_ws, size_t ws_size,
                              hipStream_t stream) {
  (void)in_sizes; (void)n_in; (void)out_size; (void)ws_size;
  const float* x = (const float*)d_in[0];
  const float* temp = (const float*)d_in[1];
  const float* qkvw = (const float*)d_in[2];
  const float* dww = (const float*)d_in[3];
  const float* projw = (const float*)d_in[4];
  float* out = (float*)d_out;

  char* ws = (char*)d_ws;
  const size_t SZQ = (size_t)288 * HW_ * 2;  // 40,144,896 B
  // [0, SZQ):      qkvb planes  -> later tout (19.7 MB overlay after k_dw)
  // [SZQ, 2*SZQ):  xbT (13.4 MB) -> qkvd planes -> predsT (13.4 MB)
  unsigned short* qkvb = (unsigned short*)ws;
  unsigned short* tout = (unsigned short*)ws;
  unsigned short* xbT = (unsigned short*)(ws + SZQ);
  unsigned short* qkvd = (unsigned short*)(ws + SZQ);
  unsigned short* predsT = (unsigned short*)(ws + SZQ);

  k_pre<<<dim3(1089), 256, 0, stream>>>(x, xbT);
  k_gemm<<<dim3(545, 3), 256, 0, stream>>>(qkvw, xbT, qkvb, nullptr, 0);
  k_dw<<<dim3(273, 36), 256, 0, stream>>>(qkvb, dww, qkvd);
  k_attn<<<dim3(64, 25), 192, 0, stream>>>(qkvd, temp, tout);
  k_avg<<<dim3(1089), 256, 0, stream>>>(tout, predsT);
  k_gemm<<<dim3(545, 1), 256, 0, stream>>>(projw, predsT, nullptr, out, 1);
}

// Round 5
// 173.239 us; speedup vs baseline: 2.4736x; 1.2680x over previous
//
#include <hip/hip_runtime.h>
#include <hip/hip_bf16.h>

#define HW_ 69696
#define W_ 264
#define H_ 264

typedef short bf16x8 __attribute__((ext_vector_type(8)));
typedef float f32x4 __attribute__((ext_vector_type(4)));

static __device__ __forceinline__ unsigned short f2b(float f) {
  __hip_bfloat16 h = __float2bfloat16(f);
  return *reinterpret_cast<unsigned short*>(&h);
}
static __device__ __forceinline__ float b2f(unsigned short u) {
  __hip_bfloat16 h;
  *reinterpret_cast<unsigned short*>(&h) = u;
  return __bfloat162float(h);
}
static __device__ __forceinline__ float lo_f(unsigned int u) {
  union { unsigned int i; float f; } c; c.i = u << 16; return c.f;
}
static __device__ __forceinline__ float hi_f(unsigned int u) {
  union { unsigned int i; float f; } c; c.i = u & 0xffff0000u; return c.f;
}

// ---------------- k_pre: roll(-4,-4) + f32->bf16 + transpose -> xbT[px][96] ----------------
__global__ __launch_bounds__(256) void k_pre(const float* __restrict__ x,
                                             unsigned short* __restrict__ xbT) {
  __shared__ unsigned short t_[96 * 70];
  __shared__ int rp[64];
  const int tid = threadIdx.x;
  const int px0 = blockIdx.x * 64;
  if (tid < 64) {
    int p = px0 + tid;
    int y = p / W_, xx = p - y * W_;
    int y2 = y + 4; if (y2 >= H_) y2 -= H_;
    int x2 = xx + 4; if (x2 >= W_) x2 -= W_;
    rp[tid] = y2 * W_ + x2;
  }
  __syncthreads();
  for (int l = tid; l < 96 * 64; l += 256) {
    int c = l >> 6, j = l & 63;
    t_[c * 70 + j] = f2b(x[c * HW_ + rp[j]]);
  }
  __syncthreads();
  const int pxl = tid >> 2, qp = tid & 3;
  unsigned int tmp[12];
#pragma unroll
  for (int i = 0; i < 12; ++i) {
    unsigned int lo = t_[(qp * 24 + 2 * i) * 70 + pxl];
    unsigned int hi = t_[(qp * 24 + 2 * i + 1) * 70 + pxl];
    tmp[i] = lo | (hi << 16);
  }
  uint4* dst = (uint4*)(xbT + (size_t)(px0 + pxl) * 96 + qp * 24);
  dst[0] = make_uint4(tmp[0], tmp[1], tmp[2], tmp[3]);
  dst[1] = make_uint4(tmp[4], tmp[5], tmp[6], tmp[7]);
  dst[2] = make_uint4(tmp[8], tmp[9], tmp[10], tmp[11]);
}

// ---------------- k_gemm: qkv = W(288x96) @ X(96xHW), MFMA bf16, plane-8 out ----------------
__global__ __launch_bounds__(256, 3) void k_gemm(const float* __restrict__ w,
                                                 const unsigned short* __restrict__ bT,
                                                 unsigned short* __restrict__ outb) {
  __shared__ __align__(16) char smem[46592];
  unsigned short* As = (unsigned short*)smem;   // [96][104]
  unsigned short* Bs = As + 96 * 104;           // [128][104]

  const int tid = threadIdx.x;
  const int px0 = blockIdx.x * 128;
  const int oc = blockIdx.y;
  const int npx = min(128, HW_ - px0);

  const float* wp = w + oc * 96 * 96;
  for (int l = tid; l < 96 * 24; l += 256) {
    int o = l / 24, c4 = (l - (l / 24) * 24) * 4;
    float4 v = *(const float4*)&wp[o * 96 + c4];
    unsigned int p0 = (unsigned int)f2b(v.x) | ((unsigned int)f2b(v.y) << 16);
    unsigned int p1 = (unsigned int)f2b(v.z) | ((unsigned int)f2b(v.w) << 16);
    *(uint2*)&As[o * 104 + c4] = make_uint2(p0, p1);
  }
  {
    const int nbytes = npx * 192;
    const char* src = (const char*)(bT + (size_t)px0 * 96);
    for (int off = tid * 16; off < nbytes; off += 256 * 16) {
      uint4 v = *(const uint4*)(src + off);
      int row = off / 192;
      int colb = off - row * 192;
      *(uint4*)((char*)Bs + row * 208 + colb) = v;
    }
  }
  __syncthreads();

  const int wid = tid >> 6, lane = tid & 63;
  const int quad = lane >> 4, lo = lane & 15;
  f32x4 acc[6][2];
#pragma unroll
  for (int mt = 0; mt < 6; ++mt)
#pragma unroll
    for (int nt = 0; nt < 2; ++nt) acc[mt][nt] = {0.f, 0.f, 0.f, 0.f};

#pragma unroll
  for (int ks = 0; ks < 3; ++ks) {
    const int kb = ks * 32 + quad * 8;
    bf16x8 b[2];
#pragma unroll
    for (int nt = 0; nt < 2; ++nt)
      b[nt] = *(const bf16x8*)&Bs[(wid * 32 + nt * 16 + lo) * 104 + kb];
#pragma unroll
    for (int mt = 0; mt < 6; ++mt) {
      bf16x8 a = *(const bf16x8*)&As[(mt * 16 + lo) * 104 + kb];
#pragma unroll
      for (int nt = 0; nt < 2; ++nt)
        acc[mt][nt] = __builtin_amdgcn_mfma_f32_16x16x32_bf16(a, b[nt], acc[mt][nt], 0, 0, 0);
    }
  }

  __syncthreads();
  unsigned short* Cs2 = (unsigned short*)smem;  // [128][104] px-major
#pragma unroll
  for (int mt = 0; mt < 6; ++mt)
#pragma unroll
    for (int nt = 0; nt < 2; ++nt) {
      int px_l = wid * 32 + nt * 16 + lo;
#pragma unroll
      for (int r = 0; r < 4; ++r)
        Cs2[px_l * 104 + mt * 16 + quad * 4 + r] = f2b(acc[mt][nt][r]);
    }
  __syncthreads();
  for (int i = tid; i < 128 * 12; i += 256) {
    int pxl = i & 127, j = i >> 7;
    if (px0 + pxl < HW_)
      *((uint4*)outb + (size_t)(oc * 12 + j) * HW_ + px0 + pxl) =
          ((const uint4*)(Cs2 + pxl * 104))[j];
  }
}

// ---------------- k_dw: 3x3 depthwise conv on plane-8 layout [36][HW][8] ----------------
__global__ __launch_bounds__(256) void k_dw(const unsigned short* __restrict__ qkv,
                                            const float* __restrict__ dw,
                                            unsigned short* __restrict__ out) {
  const int u = blockIdx.y;  // 0..35
  const int px = blockIdx.x * 256 + threadIdx.x;
  if (px >= HW_) return;
  const int y = px / W_, x = px - y * W_;
  const uint4* plane = (const uint4*)qkv + (size_t)u * HW_;
  const float* wp = dw + u * 72;
  float wv[72];
#pragma unroll
  for (int i = 0; i < 72; ++i) wv[i] = wp[i];

  float acc[8] = {0.f, 0.f, 0.f, 0.f, 0.f, 0.f, 0.f, 0.f};
#pragma unroll
  for (int dy = 0; dy < 3; ++dy) {
    const int yy = y + dy - 1;
#pragma unroll
    for (int dx = 0; dx < 3; ++dx) {
      const int xx2 = x + dx - 1;
      const int t = dy * 3 + dx;
      uint4 v = make_uint4(0u, 0u, 0u, 0u);
      if ((unsigned)yy < (unsigned)H_ && (unsigned)xx2 < (unsigned)W_)
        v = plane[yy * W_ + xx2];
      float f[8];
      f[0] = lo_f(v.x); f[1] = hi_f(v.x);
      f[2] = lo_f(v.y); f[3] = hi_f(v.y);
      f[4] = lo_f(v.z); f[5] = hi_f(v.z);
      f[6] = lo_f(v.w); f[7] = hi_f(v.w);
#pragma unroll
      for (int ci = 0; ci < 8; ++ci) acc[ci] += wv[ci * 9 + t] * f[ci];
    }
  }
  uint4 o;
  o.x = (unsigned int)f2b(acc[0]) | ((unsigned int)f2b(acc[1]) << 16);
  o.y = (unsigned int)f2b(acc[2]) | ((unsigned int)f2b(acc[3]) << 16);
  o.z = (unsigned int)f2b(acc[4]) | ((unsigned int)f2b(acc[5]) << 16);
  o.w = (unsigned int)f2b(acc[6]) | ((unsigned int)f2b(acc[7]) << 16);
  *((uint4*)out + (size_t)u * HW_ + px) = o;
}

// ---------------- k_attn: MFMA windowed channel attention (plane-8 input) ----------------
// block = (window wi, tile t), 192 thr = 3 waves, wave h = head h.
// qd: [36][HW][8] bf16. tout: [t][4096][96] bf16 RECORD-major.
#define P1 296   // shorts per px in LDS   (37 uint4)
#define P8 2376  // shorts per row of 8 px (297 uint4)
__global__ __launch_bounds__(192) void k_attn(const unsigned short* __restrict__ qd,
                                              const float* __restrict__ temp,
                                              unsigned short* __restrict__ tout) {
  __shared__ __align__(16) unsigned short flat[8 * P8];
  __shared__ __align__(16) unsigned short attnL[3 * 32 * 40];
  __shared__ float invn[3 * 32];
  const int tid = threadIdx.x;
  const int wi = blockIdx.x, t = blockIdx.y;
  const int i0 = (t / 5) * 50, j0 = (t % 5) * 50;
  const int wy = wi >> 3, wx = wi & 7;
  const int gy0 = i0 + wy * 8, gx0 = j0 + wx * 8;

  {  // stage from planes: (u, r, j) -> flat[r][j][u*8]
    const size_t base = (size_t)gy0 * W_ + gx0;
    for (int idx = tid; idx < 36 * 64; idx += 192) {
      int u = idx >> 6, rj = idx & 63, r = rj >> 3, j = rj & 7;
      uint4 v = ((const uint4*)qd)[(size_t)u * HW_ + base + r * W_ + j];
      ((uint4*)flat)[r * 297 + j * 37 + u] = v;
    }
  }
  __syncthreads();

  const int h = tid >> 6, lane = tid & 63;
  const int quad = lane >> 4, lo = lane & 15;
  const int cb = h * 32;

  bf16x8 qf[2][2], kf[2][2];
#pragma unroll
  for (int mt = 0; mt < 2; ++mt)
#pragma unroll
    for (int kt = 0; kt < 2; ++kt) {
      const int rbase = (kt * 4 + quad) * P8;
      const int cq = cb + mt * 16 + lo;
      const int ck = 96 + cb + mt * 16 + lo;
      bf16x8 q8, k8;
#pragma unroll
      for (int j = 0; j < 8; ++j) {
        q8[j] = (short)flat[rbase + j * P1 + cq];
        k8[j] = (short)flat[rbase + j * P1 + ck];
      }
      qf[mt][kt] = q8;
      kf[mt][kt] = k8;
    }

  f32x4 S[2][2];
#pragma unroll
  for (int mt = 0; mt < 2; ++mt)
#pragma unroll
    for (int nt = 0; nt < 2; ++nt) {
      S[mt][nt] = {0.f, 0.f, 0.f, 0.f};
#pragma unroll
      for (int kt = 0; kt < 2; ++kt)
        S[mt][nt] = __builtin_amdgcn_mfma_f32_16x16x32_bf16(qf[mt][kt], kf[nt][kt], S[mt][nt], 0, 0, 0);
    }

  float ivk[2];
#pragma unroll
  for (int mt = 0; mt < 2; ++mt) {
    float sq = 0.f, sk = 0.f;
#pragma unroll
    for (int kt = 0; kt < 2; ++kt)
#pragma unroll
      for (int j = 0; j < 8; ++j) {
        float a = b2f((unsigned short)qf[mt][kt][j]);
        float b = b2f((unsigned short)kf[mt][kt][j]);
        sq += a * a;
        sk += b * b;
      }
    sq += __shfl_xor(sq, 16);
    sq += __shfl_xor(sq, 32);
    sk += __shfl_xor(sk, 16);
    sk += __shfl_xor(sk, 32);
    if (quad == 0) invn[h * 32 + mt * 16 + lo] = 1.f / fmaxf(sqrtf(sq), 1e-12f);
    ivk[mt] = 1.f / fmaxf(sqrtf(sk), 1e-12f);
  }
  __syncthreads();

  const float ts = temp[h];
#pragma unroll
  for (int mt = 0; mt < 2; ++mt)
#pragma unroll
    for (int nt = 0; nt < 2; ++nt)
#pragma unroll
      for (int r = 0; r < 4; ++r) {
        int c = mt * 16 + quad * 4 + r;
        float v = S[mt][nt][r] * invn[h * 32 + c] * ivk[nt] * ts;
        attnL[(h * 32 + c) * 40 + nt * 16 + lo] = f2b(fmaxf(v, 0.f));
      }
  __syncthreads();

  bf16x8 af[2];
#pragma unroll
  for (int mt = 0; mt < 2; ++mt)
    af[mt] = *(const bf16x8*)&attnL[(h * 32 + mt * 16 + lo) * 40 + quad * 8];

  f32x4 O[2][4];
#pragma unroll
  for (int nt = 0; nt < 4; ++nt) {
    const int px = nt * 16 + lo;
    bf16x8 vf = *(const bf16x8*)&flat[(px >> 3) * P8 + (px & 7) * P1 + 192 + cb + quad * 8];
#pragma unroll
    for (int mt = 0; mt < 2; ++mt) {
      f32x4 z = {0.f, 0.f, 0.f, 0.f};
      O[mt][nt] = __builtin_amdgcn_mfma_f32_16x16x32_bf16(af[mt], vf, z, 0, 0, 0);
    }
  }
  __syncthreads();  // all flat reads complete before overlay

  // transpose O -> px-major records in LDS (overlay flat), then coalesced store
  unsigned short* Cs = flat;  // [64 px][104]
#pragma unroll
  for (int mt = 0; mt < 2; ++mt)
#pragma unroll
    for (int nt = 0; nt < 4; ++nt) {
      const int px = nt * 16 + lo;
      unsigned int p0 = (unsigned int)f2b(O[mt][nt][0]) | ((unsigned int)f2b(O[mt][nt][1]) << 16);
      unsigned int p1 = (unsigned int)f2b(O[mt][nt][2]) | ((unsigned int)f2b(O[mt][nt][3]) << 16);
      *(uint2*)&Cs[px * 104 + cb + mt * 16 + quad * 4] = make_uint2(p0, p1);
    }
  __syncthreads();

  for (int idx = tid; idx < 64 * 12; idx += 192) {
    int rec = idx / 12, u = idx - (idx / 12) * 12;
    int r = rec >> 3, j = rec & 7;
    size_t g = (size_t)t * 4096 + (wy * 8 + r) * 64 + wx * 8 + j;
    ((uint4*)tout)[g * 12 + u] = ((const uint4*)(Cs + rec * 104))[u];
  }
}

// ---------------- k_avgproj: overlap-average + 1x1 proj + roll(+4,+4), f32 out ----------------
// tout: [t][4096][96] bf16 records. 2 threads/px build averaged B-tile, then MFMA.
__global__ __launch_bounds__(256, 3) void k_avgproj(const float* __restrict__ w,
                                                    const unsigned short* __restrict__ tout,
                                                    float* __restrict__ outf) {
  __shared__ __align__(16) char smem[46592];
  unsigned short* As = (unsigned short*)smem;   // [96][104]
  unsigned short* Bs = As + 96 * 104;           // [128][104]

  const int tid = threadIdx.x;
  const int px0 = blockIdx.x * 128;

  for (int l = tid; l < 96 * 24; l += 256) {
    int o = l / 24, c4 = (l - (l / 24) * 24) * 4;
    float4 v = *(const float4*)&w[o * 96 + c4];
    unsigned int p0 = (unsigned int)f2b(v.x) | ((unsigned int)f2b(v.y) << 16);
    unsigned int p1 = (unsigned int)f2b(v.z) | ((unsigned int)f2b(v.w) << 16);
    *(uint2*)&As[o * 104 + c4] = make_uint2(p0, p1);
  }

  {  // B build: thread = (pxl, half h): average <=4 half-records (48 ch)
    const int pxl = tid >> 1, hh = tid & 1;
    const int px = px0 + pxl;
    unsigned short* bd = Bs + pxl * 104 + hh * 48;
    if (px < HW_) {
      const int y = px / W_, xx = px - y * W_;
      int loy = (y >= 64) ? (y - 14) / 50 : 0;
      int hiy = y / 50; if (hiy > 4) hiy = 4;
      int lox = (xx >= 64) ? (xx - 14) / 50 : 0;
      int hix = xx / 50; if (hix > 4) hix = 4;
      float acc[48];
#pragma unroll
      for (int i = 0; i < 48; ++i) acc[i] = 0.f;
      int cnt = 0;
      for (int ty = loy; ty <= hiy; ++ty)
        for (int tx = lox; tx <= hix; ++tx) {
          size_t rec = (size_t)(ty * 5 + tx) * 4096 + ((y - ty * 50) << 6) + (xx - tx * 50);
          const uint4* rp = (const uint4*)tout + rec * 12 + hh * 6;
#pragma unroll
          for (int ui = 0; ui < 6; ++ui) {
            uint4 v = rp[ui];
            acc[ui * 8 + 0] += lo_f(v.x); acc[ui * 8 + 1] += hi_f(v.x);
            acc[ui * 8 + 2] += lo_f(v.y); acc[ui * 8 + 3] += hi_f(v.y);
            acc[ui * 8 + 4] += lo_f(v.z); acc[ui * 8 + 5] += hi_f(v.z);
            acc[ui * 8 + 6] += lo_f(v.w); acc[ui * 8 + 7] += hi_f(v.w);
          }
          ++cnt;
        }
      const float inv = 1.f / (float)cnt;
#pragma unroll
      for (int ui = 0; ui < 6; ++ui) {
        uint4 o;
        o.x = (unsigned int)f2b(acc[ui * 8 + 0] * inv) | ((unsigned int)f2b(acc[ui * 8 + 1] * inv) << 16);
        o.y = (unsigned int)f2b(acc[ui * 8 + 2] * inv) | ((unsigned int)f2b(acc[ui * 8 + 3] * inv) << 16);
        o.z = (unsigned int)f2b(acc[ui * 8 + 4] * inv) | ((unsigned int)f2b(acc[ui * 8 + 5] * inv) << 16);
        o.w = (unsigned int)f2b(acc[ui * 8 + 6] * inv) | ((unsigned int)f2b(acc[ui * 8 + 7] * inv) << 16);
        ((uint4*)bd)[ui] = o;
      }
    } else {
      uint4 z = make_uint4(0u, 0u, 0u, 0u);
#pragma unroll
      for (int ui = 0; ui < 6; ++ui) ((uint4*)bd)[ui] = z;
    }
  }
  __syncthreads();

  const int wid = tid >> 6, lane = tid & 63;
  const int quad = lane >> 4, lo = lane & 15;
  f32x4 acc[6][2];
#pragma unroll
  for (int mt = 0; mt < 6; ++mt)
#pragma unroll
    for (int nt = 0; nt < 2; ++nt) acc[mt][nt] = {0.f, 0.f, 0.f, 0.f};

#pragma unroll
  for (int ks = 0; ks < 3; ++ks) {
    const int kb = ks * 32 + quad * 8;
    bf16x8 b[2];
#pragma unroll
    for (int nt = 0; nt < 2; ++nt)
      b[nt] = *(const bf16x8*)&Bs[(wid * 32 + nt * 16 + lo) * 104 + kb];
#pragma unroll
    for (int mt = 0; mt < 6; ++mt) {
      bf16x8 a = *(const bf16x8*)&As[(mt * 16 + lo) * 104 + kb];
#pragma unroll
      for (int nt = 0; nt < 2; ++nt)
        acc[mt][nt] = __builtin_amdgcn_mfma_f32_16x16x32_bf16(a, b[nt], acc[mt][nt], 0, 0, 0);
    }
  }

#pragma unroll
  for (int nt = 0; nt < 2; ++nt) {
    int px = px0 + wid * 32 + nt * 16 + lo;
    if (px < HW_) {
      int y = px / W_, xx = px - y * W_;
      int y2 = y + 4; if (y2 >= H_) y2 -= H_;
      int x2 = xx + 4; if (x2 >= W_) x2 -= W_;
      int tp = y2 * W_ + x2;
#pragma unroll
      for (int mt = 0; mt < 6; ++mt) {
        int row = mt * 16 + quad * 4;
#pragma unroll
        for (int r = 0; r < 4; ++r)
          outf[(size_t)(row + r) * HW_ + tp] = acc[mt][nt][r];
      }
    }
  }
}

extern "C" void kernel_launch(void* const* d_in, const int* in_sizes, int n_in,
                              void* d_out, int out_size, void* d_ws, size_t ws_size,
                              hipStream_t stream) {
  (void)in_sizes; (void)n_in; (void)out_size; (void)ws_size;
  const float* x = (const float*)d_in[0];
  const float* temp = (const float*)d_in[1];
  const float* qkvw = (const float*)d_in[2];
  const float* dww = (const float*)d_in[3];
  const float* projw = (const float*)d_in[4];
  float* out = (float*)d_out;

  char* ws = (char*)d_ws;
  const size_t SZQ = (size_t)288 * HW_ * 2;  // 40,144,896 B
  // [0, SZQ):      qkvb planes -> tout records (19.7 MB overlay after k_dw)
  // [SZQ, 2*SZQ):  xbT (13.4 MB) -> qkvd planes
  unsigned short* qkvb = (unsigned short*)ws;
  unsigned short* tout = (unsigned short*)ws;
  unsigned short* xbT = (unsigned short*)(ws + SZQ);
  unsigned short* qkvd = (unsigned short*)(ws + SZQ);

  k_pre<<<dim3(1089), 256, 0, stream>>>(x, xbT);
  k_gemm<<<dim3(545, 3), 256, 0, stream>>>(qkvw, xbT, qkvb);
  k_dw<<<dim3(273, 36), 256, 0, stream>>>(qkvb, dww, qkvd);
  k_attn<<<dim3(64, 25), 192, 0, stream>>>(qkvd, temp, tout);
  k_avgproj<<<dim3(545), 256, 0, stream>>>(projw, tout, out);
}

// Round 6
// 172.481 us; speedup vs baseline: 2.4845x; 1.0044x over previous
//
#include <hip/hip_runtime.h>
#include <hip/hip_bf16.h>

#define HW_ 69696
#define W_ 264
#define H_ 264

typedef short bf16x8 __attribute__((ext_vector_type(8)));
typedef float f32x4 __attribute__((ext_vector_type(4)));

static __device__ __forceinline__ unsigned short f2b(float f) {
  __hip_bfloat16 h = __float2bfloat16(f);
  return *reinterpret_cast<unsigned short*>(&h);
}
static __device__ __forceinline__ float b2f(unsigned short u) {
  __hip_bfloat16 h;
  *reinterpret_cast<unsigned short*>(&h) = u;
  return __bfloat162float(h);
}
static __device__ __forceinline__ float lo_f(unsigned int u) {
  union { unsigned int i; float f; } c; c.i = u << 16; return c.f;
}
static __device__ __forceinline__ float hi_f(unsigned int u) {
  union { unsigned int i; float f; } c; c.i = u & 0xffff0000u; return c.f;
}

// ---------------- k_pre: roll(-4,-4) + f32->bf16 + transpose -> xbT[px][96] ----------------
__global__ __launch_bounds__(256) void k_pre(const float* __restrict__ x,
                                             unsigned short* __restrict__ xbT) {
  __shared__ unsigned short t_[96 * 70];
  __shared__ int rp[64];
  const int tid = threadIdx.x;
  const int px0 = blockIdx.x * 64;
  if (tid < 64) {
    int p = px0 + tid;
    int y = p / W_, xx = p - y * W_;
    int y2 = y + 4; if (y2 >= H_) y2 -= H_;
    int x2 = xx + 4; if (x2 >= W_) x2 -= W_;
    rp[tid] = y2 * W_ + x2;
  }
  __syncthreads();
  for (int l = tid; l < 96 * 64; l += 256) {
    int c = l >> 6, j = l & 63;
    t_[c * 70 + j] = f2b(x[c * HW_ + rp[j]]);
  }
  __syncthreads();
  const int pxl = tid >> 2, qp = tid & 3;
  unsigned int tmp[12];
#pragma unroll
  for (int i = 0; i < 12; ++i) {
    unsigned int lo = t_[(qp * 24 + 2 * i) * 70 + pxl];
    unsigned int hi = t_[(qp * 24 + 2 * i + 1) * 70 + pxl];
    tmp[i] = lo | (hi << 16);
  }
  uint4* dst = (uint4*)(xbT + (size_t)(px0 + pxl) * 96 + qp * 24);
  dst[0] = make_uint4(tmp[0], tmp[1], tmp[2], tmp[3]);
  dst[1] = make_uint4(tmp[4], tmp[5], tmp[6], tmp[7]);
  dst[2] = make_uint4(tmp[8], tmp[9], tmp[10], tmp[11]);
}

// ---------------- k_gemm: qkv = W(288x96) @ X(96xHW), MFMA bf16, plane-8 out ----------------
__global__ __launch_bounds__(256, 3) void k_gemm(const float* __restrict__ w,
                                                 const unsigned short* __restrict__ bT,
                                                 unsigned short* __restrict__ outb) {
  __shared__ __align__(16) char smem[46592];
  unsigned short* As = (unsigned short*)smem;   // [96][104]
  unsigned short* Bs = As + 96 * 104;           // [128][104]

  const int tid = threadIdx.x;
  const int px0 = blockIdx.x * 128;
  const int oc = blockIdx.y;
  const int npx = min(128, HW_ - px0);

  const float* wp = w + oc * 96 * 96;
  for (int l = tid; l < 96 * 24; l += 256) {
    int o = l / 24, c4 = (l - (l / 24) * 24) * 4;
    float4 v = *(const float4*)&wp[o * 96 + c4];
    unsigned int p0 = (unsigned int)f2b(v.x) | ((unsigned int)f2b(v.y) << 16);
    unsigned int p1 = (unsigned int)f2b(v.z) | ((unsigned int)f2b(v.w) << 16);
    *(uint2*)&As[o * 104 + c4] = make_uint2(p0, p1);
  }
  {
    const int nbytes = npx * 192;
    const char* src = (const char*)(bT + (size_t)px0 * 96);
    for (int off = tid * 16; off < nbytes; off += 256 * 16) {
      uint4 v = *(const uint4*)(src + off);
      int row = off / 192;
      int colb = off - row * 192;
      *(uint4*)((char*)Bs + row * 208 + colb) = v;
    }
  }
  __syncthreads();

  const int wid = tid >> 6, lane = tid & 63;
  const int quad = lane >> 4, lo = lane & 15;
  f32x4 acc[6][2];
#pragma unroll
  for (int mt = 0; mt < 6; ++mt)
#pragma unroll
    for (int nt = 0; nt < 2; ++nt) acc[mt][nt] = {0.f, 0.f, 0.f, 0.f};

#pragma unroll
  for (int ks = 0; ks < 3; ++ks) {
    const int kb = ks * 32 + quad * 8;
    bf16x8 b[2];
#pragma unroll
    for (int nt = 0; nt < 2; ++nt)
      b[nt] = *(const bf16x8*)&Bs[(wid * 32 + nt * 16 + lo) * 104 + kb];
#pragma unroll
    for (int mt = 0; mt < 6; ++mt) {
      bf16x8 a = *(const bf16x8*)&As[(mt * 16 + lo) * 104 + kb];
#pragma unroll
      for (int nt = 0; nt < 2; ++nt)
        acc[mt][nt] = __builtin_amdgcn_mfma_f32_16x16x32_bf16(a, b[nt], acc[mt][nt], 0, 0, 0);
    }
  }

  __syncthreads();
  unsigned short* Cs2 = (unsigned short*)smem;  // [128][104] px-major
#pragma unroll
  for (int mt = 0; mt < 6; ++mt)
#pragma unroll
    for (int nt = 0; nt < 2; ++nt) {
      int px_l = wid * 32 + nt * 16 + lo;
#pragma unroll
      for (int r = 0; r < 4; ++r)
        Cs2[px_l * 104 + mt * 16 + quad * 4 + r] = f2b(acc[mt][nt][r]);
    }
  __syncthreads();
  for (int i = tid; i < 128 * 12; i += 256) {
    int pxl = i & 127, j = i >> 7;
    if (px0 + pxl < HW_)
      *((uint4*)outb + (size_t)(oc * 12 + j) * HW_ + px0 + pxl) =
          ((const uint4*)(Cs2 + pxl * 104))[j];
  }
}

// ---------------- k_dw: 3x3 depthwise conv, 2D-tiled LDS, plane-8 layout [36][HW][8] ----------------
// block = (x-tile 64 px, y-tile 16 rows, plane u). Stage 18x66 halo tile in LDS.
__global__ __launch_bounds__(256) void k_dw(const unsigned short* __restrict__ qkv,
                                            const float* __restrict__ dw,
                                            unsigned short* __restrict__ out) {
  __shared__ __align__(16) uint4 inS[18 * 66];  // [row][px], 19,008 B... (18*66*16 = 19008? no: 1188*16=19008)
  const int tid = threadIdx.x;
  const int x0 = blockIdx.x * 64;
  const int y0 = blockIdx.y * 16;
  const int u = blockIdx.z;  // 0..35
  const uint4* plane = (const uint4*)qkv + (size_t)u * HW_;
  const float* wp = dw + u * 72;  // uniform -> SGPR
  float wv[72];
#pragma unroll
  for (int i = 0; i < 72; ++i) wv[i] = wp[i];

  for (int idx = tid; idx < 18 * 66; idx += 256) {
    int rr = idx / 66, cc = idx - rr * 66;
    int gy = y0 - 1 + rr, gx = x0 - 1 + cc;
    uint4 v = make_uint4(0u, 0u, 0u, 0u);
    if ((unsigned)gy < (unsigned)H_ && (unsigned)gx < (unsigned)W_)
      v = plane[gy * W_ + gx];
    inS[idx] = v;
  }
  __syncthreads();

#pragma unroll
  for (int k = 0; k < 4; ++k) {
    const int oidx = k * 256 + tid;
    const int ro = oidx >> 6, co = oidx & 63;
    const int y = y0 + ro, x = x0 + co;
    float acc[8] = {0.f, 0.f, 0.f, 0.f, 0.f, 0.f, 0.f, 0.f};
#pragma unroll
    for (int dy = 0; dy < 3; ++dy)
#pragma unroll
      for (int dx = 0; dx < 3; ++dx) {
        uint4 v = inS[(ro + dy) * 66 + co + dx];
        float w0 = wv[0 * 9 + dy * 3 + dx], w1 = wv[1 * 9 + dy * 3 + dx];
        float w2 = wv[2 * 9 + dy * 3 + dx], w3 = wv[3 * 9 + dy * 3 + dx];
        float w4 = wv[4 * 9 + dy * 3 + dx], w5 = wv[5 * 9 + dy * 3 + dx];
        float w6 = wv[6 * 9 + dy * 3 + dx], w7 = wv[7 * 9 + dy * 3 + dx];
        acc[0] += w0 * lo_f(v.x); acc[1] += w1 * hi_f(v.x);
        acc[2] += w2 * lo_f(v.y); acc[3] += w3 * hi_f(v.y);
        acc[4] += w4 * lo_f(v.z); acc[5] += w5 * hi_f(v.z);
        acc[6] += w6 * lo_f(v.w); acc[7] += w7 * hi_f(v.w);
      }
    if (y < H_ && x < W_) {
      uint4 o;
      o.x = (unsigned int)f2b(acc[0]) | ((unsigned int)f2b(acc[1]) << 16);
      o.y = (unsigned int)f2b(acc[2]) | ((unsigned int)f2b(acc[3]) << 16);
      o.z = (unsigned int)f2b(acc[4]) | ((unsigned int)f2b(acc[5]) << 16);
      o.w = (unsigned int)f2b(acc[6]) | ((unsigned int)f2b(acc[7]) << 16);
      *((uint4*)out + (size_t)u * HW_ + y * W_ + x) = o;
    }
  }
}

// ---------------- k_attn: MFMA windowed channel attention (plane-8 input) ----------------
// block = (window wi, tile t), 192 thr = 3 waves, wave h = head h.
// qd: [36][HW][8] bf16. tout: [t][4096][96] bf16 RECORD-major.
#define P1 296   // shorts per px in LDS   (37 uint4)
#define P8 2376  // shorts per row of 8 px (297 uint4)
__global__ __launch_bounds__(192) void k_attn(const unsigned short* __restrict__ qd,
                                              const float* __restrict__ temp,
                                              unsigned short* __restrict__ tout) {
  __shared__ __align__(16) unsigned short flat[8 * P8];
  __shared__ __align__(16) unsigned short attnL[3 * 32 * 40];
  __shared__ float invn[3 * 32];
  const int tid = threadIdx.x;
  const int wi = blockIdx.x, t = blockIdx.y;
  const int i0 = (t / 5) * 50, j0 = (t % 5) * 50;
  const int wy = wi >> 3, wx = wi & 7;
  const int gy0 = i0 + wy * 8, gx0 = j0 + wx * 8;

  {  // stage from planes: (u, r, j) -> flat[r][j][u*8]
    const size_t base = (size_t)gy0 * W_ + gx0;
    for (int idx = tid; idx < 36 * 64; idx += 192) {
      int u = idx >> 6, rj = idx & 63, r = rj >> 3, j = rj & 7;
      uint4 v = ((const uint4*)qd)[(size_t)u * HW_ + base + r * W_ + j];
      ((uint4*)flat)[r * 297 + j * 37 + u] = v;
    }
  }
  __syncthreads();

  const int h = tid >> 6, lane = tid & 63;
  const int quad = lane >> 4, lo = lane & 15;
  const int cb = h * 32;

  bf16x8 qf[2][2], kf[2][2];
#pragma unroll
  for (int mt = 0; mt < 2; ++mt)
#pragma unroll
    for (int kt = 0; kt < 2; ++kt) {
      const int rbase = (kt * 4 + quad) * P8;
      const int cq = cb + mt * 16 + lo;
      const int ck = 96 + cb + mt * 16 + lo;
      bf16x8 q8, k8;
#pragma unroll
      for (int j = 0; j < 8; ++j) {
        q8[j] = (short)flat[rbase + j * P1 + cq];
        k8[j] = (short)flat[rbase + j * P1 + ck];
      }
      qf[mt][kt] = q8;
      kf[mt][kt] = k8;
    }

  f32x4 S[2][2];
#pragma unroll
  for (int mt = 0; mt < 2; ++mt)
#pragma unroll
    for (int nt = 0; nt < 2; ++nt) {
      S[mt][nt] = {0.f, 0.f, 0.f, 0.f};
#pragma unroll
      for (int kt = 0; kt < 2; ++kt)
        S[mt][nt] = __builtin_amdgcn_mfma_f32_16x16x32_bf16(qf[mt][kt], kf[nt][kt], S[mt][nt], 0, 0, 0);
    }

  float ivk[2];
#pragma unroll
  for (int mt = 0; mt < 2; ++mt) {
    float sq = 0.f, sk = 0.f;
#pragma unroll
    for (int kt = 0; kt < 2; ++kt)
#pragma unroll
      for (int j = 0; j < 8; ++j) {
        float a = b2f((unsigned short)qf[mt][kt][j]);
        float b = b2f((unsigned short)kf[mt][kt][j]);
        sq += a * a;
        sk += b * b;
      }
    sq += __shfl_xor(sq, 16);
    sq += __shfl_xor(sq, 32);
    sk += __shfl_xor(sk, 16);
    sk += __shfl_xor(sk, 32);
    if (quad == 0) invn[h * 32 + mt * 16 + lo] = 1.f / fmaxf(sqrtf(sq), 1e-12f);
    ivk[mt] = 1.f / fmaxf(sqrtf(sk), 1e-12f);
  }
  __syncthreads();

  const float ts = temp[h];
#pragma unroll
  for (int mt = 0; mt < 2; ++mt)
#pragma unroll
    for (int nt = 0; nt < 2; ++nt)
#pragma unroll
      for (int r = 0; r < 4; ++r) {
        int c = mt * 16 + quad * 4 + r;
        float v = S[mt][nt][r] * invn[h * 32 + c] * ivk[nt] * ts;
        attnL[(h * 32 + c) * 40 + nt * 16 + lo] = f2b(fmaxf(v, 0.f));
      }
  __syncthreads();

  bf16x8 af[2];
#pragma unroll
  for (int mt = 0; mt < 2; ++mt)
    af[mt] = *(const bf16x8*)&attnL[(h * 32 + mt * 16 + lo) * 40 + quad * 8];

  f32x4 O[2][4];
#pragma unroll
  for (int nt = 0; nt < 4; ++nt) {
    const int px = nt * 16 + lo;
    bf16x8 vf = *(const bf16x8*)&flat[(px >> 3) * P8 + (px & 7) * P1 + 192 + cb + quad * 8];
#pragma unroll
    for (int mt = 0; mt < 2; ++mt) {
      f32x4 z = {0.f, 0.f, 0.f, 0.f};
      O[mt][nt] = __builtin_amdgcn_mfma_f32_16x16x32_bf16(af[mt], vf, z, 0, 0, 0);
    }
  }
  __syncthreads();  // all flat reads complete before overlay

  // transpose O -> px-major records in LDS (overlay flat), then coalesced store
  unsigned short* Cs = flat;  // [64 px][104]
#pragma unroll
  for (int mt = 0; mt < 2; ++mt)
#pragma unroll
    for (int nt = 0; nt < 4; ++nt) {
      const int px = nt * 16 + lo;
      unsigned int p0 = (unsigned int)f2b(O[mt][nt][0]) | ((unsigned int)f2b(O[mt][nt][1]) << 16);
      unsigned int p1 = (unsigned int)f2b(O[mt][nt][2]) | ((unsigned int)f2b(O[mt][nt][3]) << 16);
      *(uint2*)&Cs[px * 104 + cb + mt * 16 + quad * 4] = make_uint2(p0, p1);
    }
  __syncthreads();

  for (int idx = tid; idx < 64 * 12; idx += 192) {
    int rec = idx / 12, u = idx - (idx / 12) * 12;
    int r = rec >> 3, j = rec & 7;
    size_t g = (size_t)t * 4096 + (wy * 8 + r) * 64 + wx * 8 + j;
    ((uint4*)tout)[g * 12 + u] = ((const uint4*)(Cs + rec * 104))[u];
  }
}

// ---------------- k_avgproj: overlap-average + 1x1 proj + roll(+4,+4), f32 out ----------------
// tout: [t][4096][96] bf16 records. BN=64: 4 threads/px build averaged B-tile, then MFMA.
__global__ __launch_bounds__(256, 4) void k_avgproj(const float* __restrict__ w,
                                                    const unsigned short* __restrict__ tout,
                                                    float* __restrict__ outf) {
  __shared__ __align__(16) char smem[33280];
  unsigned short* As = (unsigned short*)smem;   // [96][104]
  unsigned short* Bs = As + 96 * 104;           // [64][104]

  const int tid = threadIdx.x;
  const int px0 = blockIdx.x * 64;

  for (int l = tid; l < 96 * 24; l += 256) {
    int o = l / 24, c4 = (l - (l / 24) * 24) * 4;
    float4 v = *(const float4*)&w[o * 96 + c4];
    unsigned int p0 = (unsigned int)f2b(v.x) | ((unsigned int)f2b(v.y) << 16);
    unsigned int p1 = (unsigned int)f2b(v.z) | ((unsigned int)f2b(v.w) << 16);
    *(uint2*)&As[o * 104 + c4] = make_uint2(p0, p1);
  }

  {  // B build: thread = (pxl, quarter q): average <=4 quarter-records (24 ch)
    const int pxl = tid >> 2, q = tid & 3;
    const int px = px0 + pxl;  // always < HW_ (1089*64 == HW_)
    unsigned short* bd = Bs + pxl * 104 + q * 24;
    const int y = px / W_, xx = px - y * W_;
    int loy = (y >= 64) ? (y - 14) / 50 : 0;
    int hiy = y / 50; if (hiy > 4) hiy = 4;
    int lox = (xx >= 64) ? (xx - 14) / 50 : 0;
    int hix = xx / 50; if (hix > 4) hix = 4;
    float acc[24];
#pragma unroll
    for (int i = 0; i < 24; ++i) acc[i] = 0.f;
    int cnt = 0;
    for (int ty = loy; ty <= hiy; ++ty)
      for (int tx = lox; tx <= hix; ++tx) {
        size_t rec = (size_t)(ty * 5 + tx) * 4096 + ((y - ty * 50) << 6) + (xx - tx * 50);
        const uint4* rp = (const uint4*)tout + rec * 12 + q * 3;
#pragma unroll
        for (int ui = 0; ui < 3; ++ui) {
          uint4 v = rp[ui];
          acc[ui * 8 + 0] += lo_f(v.x); acc[ui * 8 + 1] += hi_f(v.x);
          acc[ui * 8 + 2] += lo_f(v.y); acc[ui * 8 + 3] += hi_f(v.y);
          acc[ui * 8 + 4] += lo_f(v.z); acc[ui * 8 + 5] += hi_f(v.z);
          acc[ui * 8 + 6] += lo_f(v.w); acc[ui * 8 + 7] += hi_f(v.w);
        }
        ++cnt;
      }
    const float inv = 1.f / (float)cnt;
#pragma unroll
    for (int ui = 0; ui < 3; ++ui) {
      uint4 o;
      o.x = (unsigned int)f2b(acc[ui * 8 + 0] * inv) | ((unsigned int)f2b(acc[ui * 8 + 1] * inv) << 16);
      o.y = (unsigned int)f2b(acc[ui * 8 + 2] * inv) | ((unsigned int)f2b(acc[ui * 8 + 3] * inv) << 16);
      o.z = (unsigned int)f2b(acc[ui * 8 + 4] * inv) | ((unsigned int)f2b(acc[ui * 8 + 5] * inv) << 16);
      o.w = (unsigned int)f2b(acc[ui * 8 + 6] * inv) | ((unsigned int)f2b(acc[ui * 8 + 7] * inv) << 16);
      ((uint4*)bd)[ui] = o;
    }
  }
  __syncthreads();

  const int wid = tid >> 6, lane = tid & 63;
  const int quad = lane >> 4, lo = lane & 15;
  f32x4 acc[6];
#pragma unroll
  for (int mt = 0; mt < 6; ++mt) acc[mt] = {0.f, 0.f, 0.f, 0.f};

#pragma unroll
  for (int ks = 0; ks < 3; ++ks) {
    const int kb = ks * 32 + quad * 8;
    bf16x8 b = *(const bf16x8*)&Bs[(wid * 16 + lo) * 104 + kb];
#pragma unroll
    for (int mt = 0; mt < 6; ++mt) {
      bf16x8 a = *(const bf16x8*)&As[(mt * 16 + lo) * 104 + kb];
      acc[mt] = __builtin_amdgcn_mfma_f32_16x16x32_bf16(a, b, acc[mt], 0, 0, 0);
    }
  }

  {
    int px = px0 + wid * 16 + lo;
    int y = px / W_, xx = px - y * W_;
    int y2 = y + 4; if (y2 >= H_) y2 -= H_;
    int x2 = xx + 4; if (x2 >= W_) x2 -= W_;
    int tp = y2 * W_ + x2;
#pragma unroll
    for (int mt = 0; mt < 6; ++mt) {
      int row = mt * 16 + quad * 4;
#pragma unroll
      for (int r = 0; r < 4; ++r)
        outf[(size_t)(row + r) * HW_ + tp] = acc[mt][r];
    }
  }
}

extern "C" void kernel_launch(void* const* d_in, const int* in_sizes, int n_in,
                              void* d_out, int out_size, void* d_ws, size_t ws_size,
                              hipStream_t stream) {
  (void)in_sizes; (void)n_in; (void)out_size; (void)ws_size;
  const float* x = (const float*)d_in[0];
  const float* temp = (const float*)d_in[1];
  const float* qkvw = (const float*)d_in[2];
  const float* dww = (const float*)d_in[3];
  const float* projw = (const float*)d_in[4];
  float* out = (float*)d_out;

  char* ws = (char*)d_ws;
  const size_t SZQ = (size_t)288 * HW_ * 2;  // 40,144,896 B
  // [0, SZQ):      qkvb planes -> tout records (19.7 MB overlay after k_dw)
  // [SZQ, 2*SZQ):  xbT (13.4 MB) -> qkvd planes
  unsigned short* qkvb = (unsigned short*)ws;
  unsigned short* tout = (unsigned short*)ws;
  unsigned short* xbT = (unsigned short*)(ws + SZQ);
  unsigned short* qkvd = (unsigned short*)(ws + SZQ);

  k_pre<<<dim3(1089), 256, 0, stream>>>(x, xbT);
  k_gemm<<<dim3(545, 3), 256, 0, stream>>>(qkvw, xbT, qkvb);
  k_dw<<<dim3(5, 17, 36), 256, 0, stream>>>(qkvb, dww, qkvd);
  k_attn<<<dim3(64, 25), 192, 0, stream>>>(qkvd, temp, tout);
  k_avgproj<<<dim3(1089), 256, 0, stream>>>(projw, tout, out);
}

// Round 7
// 163.355 us; speedup vs baseline: 2.6233x; 1.0559x over previous
//
#include <hip/hip_runtime.h>
#include <hip/hip_bf16.h>

#define HW_ 69696
#define W_ 264
#define H_ 264

typedef short bf16x8 __attribute__((ext_vector_type(8)));
typedef float f32x4 __attribute__((ext_vector_type(4)));

static __device__ __forceinline__ unsigned short f2b(float f) {
  __hip_bfloat16 h = __float2bfloat16(f);
  return *reinterpret_cast<unsigned short*>(&h);
}
static __device__ __forceinline__ float b2f(unsigned short u) {
  __hip_bfloat16 h;
  *reinterpret_cast<unsigned short*>(&h) = u;
  return __bfloat162float(h);
}
static __device__ __forceinline__ float lo_f(unsigned int u) {
  union { unsigned int i; float f; } c; c.i = u << 16; return c.f;
}
static __device__ __forceinline__ float hi_f(unsigned int u) {
  union { unsigned int i; float f; } c; c.i = u & 0xffff0000u; return c.f;
}

// ---------------- k_gemm: qkv = W(288x96) @ roll(x), fused pre, MFMA bf16, plane-8 out ----------------
// Each block: B-tile built directly from x (roll + f32->bf16). grid (545, 3).
__global__ __launch_bounds__(256, 3) void k_gemm(const float* __restrict__ x,
                                                 const float* __restrict__ w,
                                                 unsigned short* __restrict__ outb) {
  __shared__ __align__(16) char smem[46592];
  __shared__ int rp[128];
  unsigned short* As = (unsigned short*)smem;   // [96][104]
  unsigned short* Bs = As + 96 * 104;           // [128][104]

  const int tid = threadIdx.x;
  const int px0 = blockIdx.x * 128;
  const int oc = blockIdx.y;

  if (tid < 128) {
    int p = px0 + tid;
    int r = 0;
    if (p < HW_) {
      int y = p / W_, xx = p - y * W_;
      int y2 = y + 4; if (y2 >= H_) y2 -= H_;
      int x2 = xx + 4; if (x2 >= W_) x2 -= W_;
      r = y2 * W_ + x2;
    }
    rp[tid] = r;
  }

  // stage A: 96x96 f32 -> bf16, pitch 104
  const float* wp = w + oc * 96 * 96;
  for (int l = tid; l < 96 * 24; l += 256) {
    int o = l / 24, c4 = (l - (l / 24) * 24) * 4;
    float4 v = *(const float4*)&wp[o * 96 + c4];
    unsigned int p0 = (unsigned int)f2b(v.x) | ((unsigned int)f2b(v.y) << 16);
    unsigned int p1 = (unsigned int)f2b(v.z) | ((unsigned int)f2b(v.w) << 16);
    *(uint2*)&As[o * 104 + c4] = make_uint2(p0, p1);
  }
  __syncthreads();  // rp ready

  // stage B from x directly: task = (pxl, group g of 8 ch)
  for (int l = tid; l < 128 * 12; l += 256) {
    int pxl = l & 127, g = l >> 7;
    uint4 o = make_uint4(0u, 0u, 0u, 0u);
    if (px0 + pxl < HW_) {
      const int base = rp[pxl];
      const float* xp = x + (size_t)(g * 8) * HW_ + base;
      float f0 = xp[0];
      float f1 = xp[HW_];
      float f2 = xp[2 * HW_];
      float f3 = xp[3 * HW_];
      float f4 = xp[4 * HW_];
      float f5 = xp[5 * HW_];
      float f6 = xp[6 * HW_];
      float f7 = xp[7 * HW_];
      o.x = (unsigned int)f2b(f0) | ((unsigned int)f2b(f1) << 16);
      o.y = (unsigned int)f2b(f2) | ((unsigned int)f2b(f3) << 16);
      o.z = (unsigned int)f2b(f4) | ((unsigned int)f2b(f5) << 16);
      o.w = (unsigned int)f2b(f6) | ((unsigned int)f2b(f7) << 16);
    }
    *(uint4*)&Bs[pxl * 104 + g * 8] = o;
  }
  __syncthreads();

  const int wid = tid >> 6, lane = tid & 63;
  const int quad = lane >> 4, lo = lane & 15;
  f32x4 acc[6][2];
#pragma unroll
  for (int mt = 0; mt < 6; ++mt)
#pragma unroll
    for (int nt = 0; nt < 2; ++nt) acc[mt][nt] = {0.f, 0.f, 0.f, 0.f};

#pragma unroll
  for (int ks = 0; ks < 3; ++ks) {
    const int kb = ks * 32 + quad * 8;
    bf16x8 b[2];
#pragma unroll
    for (int nt = 0; nt < 2; ++nt)
      b[nt] = *(const bf16x8*)&Bs[(wid * 32 + nt * 16 + lo) * 104 + kb];
#pragma unroll
    for (int mt = 0; mt < 6; ++mt) {
      bf16x8 a = *(const bf16x8*)&As[(mt * 16 + lo) * 104 + kb];
#pragma unroll
      for (int nt = 0; nt < 2; ++nt)
        acc[mt][nt] = __builtin_amdgcn_mfma_f32_16x16x32_bf16(a, b[nt], acc[mt][nt], 0, 0, 0);
    }
  }

  __syncthreads();
  unsigned short* Cs2 = (unsigned short*)smem;  // [128][104] px-major overlay
#pragma unroll
  for (int mt = 0; mt < 6; ++mt)
#pragma unroll
    for (int nt = 0; nt < 2; ++nt) {
      int px_l = wid * 32 + nt * 16 + lo;
#pragma unroll
      for (int r = 0; r < 4; ++r)
        Cs2[px_l * 104 + mt * 16 + quad * 4 + r] = f2b(acc[mt][nt][r]);
    }
  __syncthreads();
  for (int i = tid; i < 128 * 12; i += 256) {
    int pxl = i & 127, j = i >> 7;
    if (px0 + pxl < HW_)
      *((uint4*)outb + (size_t)(oc * 12 + j) * HW_ + px0 + pxl) =
          ((const uint4*)(Cs2 + pxl * 104))[j];
  }
}

// ---------------- k_dw: 3x3 depthwise conv, 2D-tiled LDS, plane-8 layout [36][HW][8] ----------------
__global__ __launch_bounds__(256) void k_dw(const unsigned short* __restrict__ qkv,
                                            const float* __restrict__ dw,
                                            unsigned short* __restrict__ out) {
  __shared__ __align__(16) uint4 inS[18 * 66];
  const int tid = threadIdx.x;
  const int x0 = blockIdx.x * 64;
  const int y0 = blockIdx.y * 16;
  const int u = blockIdx.z;  // 0..35
  const uint4* plane = (const uint4*)qkv + (size_t)u * HW_;
  const float* wp = dw + u * 72;
  float wv[72];
#pragma unroll
  for (int i = 0; i < 72; ++i) wv[i] = wp[i];

  for (int idx = tid; idx < 18 * 66; idx += 256) {
    int rr = idx / 66, cc = idx - rr * 66;
    int gy = y0 - 1 + rr, gx = x0 - 1 + cc;
    uint4 v = make_uint4(0u, 0u, 0u, 0u);
    if ((unsigned)gy < (unsigned)H_ && (unsigned)gx < (unsigned)W_)
      v = plane[gy * W_ + gx];
    inS[idx] = v;
  }
  __syncthreads();

#pragma unroll
  for (int k = 0; k < 4; ++k) {
    const int oidx = k * 256 + tid;
    const int ro = oidx >> 6, co = oidx & 63;
    const int y = y0 + ro, x = x0 + co;
    float acc[8] = {0.f, 0.f, 0.f, 0.f, 0.f, 0.f, 0.f, 0.f};
#pragma unroll
    for (int dy = 0; dy < 3; ++dy)
#pragma unroll
      for (int dx = 0; dx < 3; ++dx) {
        uint4 v = inS[(ro + dy) * 66 + co + dx];
        float w0 = wv[0 * 9 + dy * 3 + dx], w1 = wv[1 * 9 + dy * 3 + dx];
        float w2 = wv[2 * 9 + dy * 3 + dx], w3 = wv[3 * 9 + dy * 3 + dx];
        float w4 = wv[4 * 9 + dy * 3 + dx], w5 = wv[5 * 9 + dy * 3 + dx];
        float w6 = wv[6 * 9 + dy * 3 + dx], w7 = wv[7 * 9 + dy * 3 + dx];
        acc[0] += w0 * lo_f(v.x); acc[1] += w1 * hi_f(v.x);
        acc[2] += w2 * lo_f(v.y); acc[3] += w3 * hi_f(v.y);
        acc[4] += w4 * lo_f(v.z); acc[5] += w5 * hi_f(v.z);
        acc[6] += w6 * lo_f(v.w); acc[7] += w7 * hi_f(v.w);
      }
    if (y < H_ && x < W_) {
      uint4 o;
      o.x = (unsigned int)f2b(acc[0]) | ((unsigned int)f2b(acc[1]) << 16);
      o.y = (unsigned int)f2b(acc[2]) | ((unsigned int)f2b(acc[3]) << 16);
      o.z = (unsigned int)f2b(acc[4]) | ((unsigned int)f2b(acc[5]) << 16);
      o.w = (unsigned int)f2b(acc[6]) | ((unsigned int)f2b(acc[7]) << 16);
      *((uint4*)out + (size_t)u * HW_ + y * W_ + x) = o;
    }
  }
}

// ---------------- k_attn: MFMA windowed channel attention, V direct-from-global ----------------
// block = (window wi, tile t), 192 thr = 3 waves, wave h = head h.
// qd: [36][HW][8] bf16. tout: [t][4096][96] bf16 RECORD-major.
#define P1 200   // shorts per px in LDS (q,k only: 192 + 8 pad; 25 uint4)
#define P8 1608  // shorts per row of 8 px (201 uint4)
__global__ __launch_bounds__(192) void k_attn(const unsigned short* __restrict__ qd,
                                              const float* __restrict__ temp,
                                              unsigned short* __restrict__ tout) {
  __shared__ __align__(16) unsigned short flat[8 * P8];    // 25,728 B
  __shared__ __align__(16) unsigned short attnL[3 * 32 * 40];
  __shared__ float invn[3 * 32];
  const int tid = threadIdx.x;
  const int wi = blockIdx.x, t = blockIdx.y;
  const int i0 = (t / 5) * 50, j0 = (t % 5) * 50;
  const int wy = wi >> 3, wx = wi & 7;
  const int gy0 = i0 + wy * 8, gx0 = j0 + wx * 8;

  {  // stage q,k planes (0..23): (u, r, j) -> flat[r][j][u*8]
    const size_t base = (size_t)gy0 * W_ + gx0;
    for (int idx = tid; idx < 24 * 64; idx += 192) {
      int u = idx >> 6, rj = idx & 63, r = rj >> 3, j = rj & 7;
      uint4 v = ((const uint4*)qd)[(size_t)u * HW_ + base + r * W_ + j];
      ((uint4*)flat)[r * 201 + j * 25 + u] = v;
    }
  }
  __syncthreads();

  const int h = tid >> 6, lane = tid & 63;
  const int quad = lane >> 4, lo = lane & 15;
  const int cb = h * 32;

  bf16x8 qf[2][2], kf[2][2];
#pragma unroll
  for (int mt = 0; mt < 2; ++mt)
#pragma unroll
    for (int kt = 0; kt < 2; ++kt) {
      const int rbase = (kt * 4 + quad) * P8;
      const int cq = cb + mt * 16 + lo;
      const int ck = 96 + cb + mt * 16 + lo;
      bf16x8 q8, k8;
#pragma unroll
      for (int j = 0; j < 8; ++j) {
        q8[j] = (short)flat[rbase + j * P1 + cq];
        k8[j] = (short)flat[rbase + j * P1 + ck];
      }
      qf[mt][kt] = q8;
      kf[mt][kt] = k8;
    }

  f32x4 S[2][2];
#pragma unroll
  for (int mt = 0; mt < 2; ++mt)
#pragma unroll
    for (int nt = 0; nt < 2; ++nt) {
      S[mt][nt] = {0.f, 0.f, 0.f, 0.f};
#pragma unroll
      for (int kt = 0; kt < 2; ++kt)
        S[mt][nt] = __builtin_amdgcn_mfma_f32_16x16x32_bf16(qf[mt][kt], kf[nt][kt], S[mt][nt], 0, 0, 0);
    }

  float ivk[2];
#pragma unroll
  for (int mt = 0; mt < 2; ++mt) {
    float sq = 0.f, sk = 0.f;
#pragma unroll
    for (int kt = 0; kt < 2; ++kt)
#pragma unroll
      for (int j = 0; j < 8; ++j) {
        float a = b2f((unsigned short)qf[mt][kt][j]);
        float b = b2f((unsigned short)kf[mt][kt][j]);
        sq += a * a;
        sk += b * b;
      }
    sq += __shfl_xor(sq, 16);
    sq += __shfl_xor(sq, 32);
    sk += __shfl_xor(sk, 16);
    sk += __shfl_xor(sk, 32);
    if (quad == 0) invn[h * 32 + mt * 16 + lo] = 1.f / fmaxf(sqrtf(sq), 1e-12f);
    ivk[mt] = 1.f / fmaxf(sqrtf(sk), 1e-12f);
  }
  __syncthreads();

  const float ts = temp[h];
#pragma unroll
  for (int mt = 0; mt < 2; ++mt)
#pragma unroll
    for (int nt = 0; nt < 2; ++nt)
#pragma unroll
      for (int r = 0; r < 4; ++r) {
        int c = mt * 16 + quad * 4 + r;
        float v = S[mt][nt][r] * invn[h * 32 + c] * ivk[nt] * ts;
        attnL[(h * 32 + c) * 40 + nt * 16 + lo] = f2b(fmaxf(v, 0.f));
      }
  __syncthreads();

  bf16x8 af[2];
#pragma unroll
  for (int mt = 0; mt < 2; ++mt)
    af[mt] = *(const bf16x8*)&attnL[(h * 32 + mt * 16 + lo) * 40 + quad * 8];

  // V fragments: direct global uint4 (plane 24 + h*4 + quad, 8 contiguous channels)
  const int uv = 24 + h * 4 + quad;
  f32x4 O[2][4];
#pragma unroll
  for (int nt = 0; nt < 4; ++nt) {
    const int px = nt * 16 + lo;
    const size_t gpx = (size_t)(gy0 + (px >> 3)) * W_ + gx0 + (px & 7);
    uint4 vraw = ((const uint4*)qd)[(size_t)uv * HW_ + gpx];
    bf16x8 vf = *reinterpret_cast<bf16x8*>(&vraw);
#pragma unroll
    for (int mt = 0; mt < 2; ++mt) {
      f32x4 z = {0.f, 0.f, 0.f, 0.f};
      O[mt][nt] = __builtin_amdgcn_mfma_f32_16x16x32_bf16(af[mt], vf, z, 0, 0, 0);
    }
  }
  __syncthreads();  // all flat reads complete before overlay

  unsigned short* Cs = flat;  // [64 px][104] overlay
#pragma unroll
  for (int mt = 0; mt < 2; ++mt)
#pragma unroll
    for (int nt = 0; nt < 4; ++nt) {
      const int px = nt * 16 + lo;
      unsigned int p0 = (unsigned int)f2b(O[mt][nt][0]) | ((unsigned int)f2b(O[mt][nt][1]) << 16);
      unsigned int p1 = (unsigned int)f2b(O[mt][nt][2]) | ((unsigned int)f2b(O[mt][nt][3]) << 16);
      *(uint2*)&Cs[px * 104 + cb + mt * 16 + quad * 4] = make_uint2(p0, p1);
    }
  __syncthreads();

  for (int idx = tid; idx < 64 * 12; idx += 192) {
    int rec = idx / 12, u = idx - (idx / 12) * 12;
    int r = rec >> 3, j = rec & 7;
    size_t g = (size_t)t * 4096 + (wy * 8 + r) * 64 + wx * 8 + j;
    ((uint4*)tout)[g * 12 + u] = ((const uint4*)(Cs + rec * 104))[u];
  }
}

// ---------------- k_avgproj: overlap-average + 1x1 proj + roll(+4,+4), f32 out ----------------
__global__ __launch_bounds__(256, 4) void k_avgproj(const float* __restrict__ w,
                                                    const unsigned short* __restrict__ tout,
                                                    float* __restrict__ outf) {
  __shared__ __align__(16) char smem[33280];
  unsigned short* As = (unsigned short*)smem;   // [96][104]
  unsigned short* Bs = As + 96 * 104;           // [64][104]

  const int tid = threadIdx.x;
  const int px0 = blockIdx.x * 64;

  for (int l = tid; l < 96 * 24; l += 256) {
    int o = l / 24, c4 = (l - (l / 24) * 24) * 4;
    float4 v = *(const float4*)&w[o * 96 + c4];
    unsigned int p0 = (unsigned int)f2b(v.x) | ((unsigned int)f2b(v.y) << 16);
    unsigned int p1 = (unsigned int)f2b(v.z) | ((unsigned int)f2b(v.w) << 16);
    *(uint2*)&As[o * 104 + c4] = make_uint2(p0, p1);
  }

  {
    const int pxl = tid >> 2, q = tid & 3;
    const int px = px0 + pxl;
    unsigned short* bd = Bs + pxl * 104 + q * 24;
    const int y = px / W_, xx = px - y * W_;
    int loy = (y >= 64) ? (y - 14) / 50 : 0;
    int hiy = y / 50; if (hiy > 4) hiy = 4;
    int lox = (xx >= 64) ? (xx - 14) / 50 : 0;
    int hix = xx / 50; if (hix > 4) hix = 4;
    float acc[24];
#pragma unroll
    for (int i = 0; i < 24; ++i) acc[i] = 0.f;
    int cnt = 0;
    for (int ty = loy; ty <= hiy; ++ty)
      for (int tx = lox; tx <= hix; ++tx) {
        size_t rec = (size_t)(ty * 5 + tx) * 4096 + ((y - ty * 50) << 6) + (xx - tx * 50);
        const uint4* rp = (const uint4*)tout + rec * 12 + q * 3;
#pragma unroll
        for (int ui = 0; ui < 3; ++ui) {
          uint4 v = rp[ui];
          acc[ui * 8 + 0] += lo_f(v.x); acc[ui * 8 + 1] += hi_f(v.x);
          acc[ui * 8 + 2] += lo_f(v.y); acc[ui * 8 + 3] += hi_f(v.y);
          acc[ui * 8 + 4] += lo_f(v.z); acc[ui * 8 + 5] += hi_f(v.z);
          acc[ui * 8 + 6] += lo_f(v.w); acc[ui * 8 + 7] += hi_f(v.w);
        }
        ++cnt;
      }
    const float inv = 1.f / (float)cnt;
#pragma unroll
    for (int ui = 0; ui < 3; ++ui) {
      uint4 o;
      o.x = (unsigned int)f2b(acc[ui * 8 + 0] * inv) | ((unsigned int)f2b(acc[ui * 8 + 1] * inv) << 16);
      o.y = (unsigned int)f2b(acc[ui * 8 + 2] * inv) | ((unsigned int)f2b(acc[ui * 8 + 3] * inv) << 16);
      o.z = (unsigned int)f2b(acc[ui * 8 + 4] * inv) | ((unsigned int)f2b(acc[ui * 8 + 5] * inv) << 16);
      o.w = (unsigned int)f2b(acc[ui * 8 + 6] * inv) | ((unsigned int)f2b(acc[ui * 8 + 7] * inv) << 16);
      ((uint4*)bd)[ui] = o;
    }
  }
  __syncthreads();

  const int wid = tid >> 6, lane = tid & 63;
  const int quad = lane >> 4, lo = lane & 15;
  f32x4 acc[6];
#pragma unroll
  for (int mt = 0; mt < 6; ++mt) acc[mt] = {0.f, 0.f, 0.f, 0.f};

#pragma unroll
  for (int ks = 0; ks < 3; ++ks) {
    const int kb = ks * 32 + quad * 8;
    bf16x8 b = *(const bf16x8*)&Bs[(wid * 16 + lo) * 104 + kb];
#pragma unroll
    for (int mt = 0; mt < 6; ++mt) {
      bf16x8 a = *(const bf16x8*)&As[(mt * 16 + lo) * 104 + kb];
      acc[mt] = __builtin_amdgcn_mfma_f32_16x16x32_bf16(a, b, acc[mt], 0, 0, 0);
    }
  }

  {
    int px = px0 + wid * 16 + lo;
    int y = px / W_, xx = px - y * W_;
    int y2 = y + 4; if (y2 >= H_) y2 -= H_;
    int x2 = xx + 4; if (x2 >= W_) x2 -= W_;
    int tp = y2 * W_ + x2;
#pragma unroll
    for (int mt = 0; mt < 6; ++mt) {
      int row = mt * 16 + quad * 4;
#pragma unroll
      for (int r = 0; r < 4; ++r)
        outf[(size_t)(row + r) * HW_ + tp] = acc[mt][r];
    }
  }
}

extern "C" void kernel_launch(void* const* d_in, const int* in_sizes, int n_in,
                              void* d_out, int out_size, void* d_ws, size_t ws_size,
                              hipStream_t stream) {
  (void)in_sizes; (void)n_in; (void)out_size; (void)ws_size;
  const float* x = (const float*)d_in[0];
  const float* temp = (const float*)d_in[1];
  const float* qkvw = (const float*)d_in[2];
  const float* dww = (const float*)d_in[3];
  const float* projw = (const float*)d_in[4];
  float* out = (float*)d_out;

  char* ws = (char*)d_ws;
  const size_t SZQ = (size_t)288 * HW_ * 2;  // 40,144,896 B
  // [0, SZQ):      qkvb planes -> tout records (19.7 MB overlay after k_dw)
  // [SZQ, 2*SZQ):  qkvd planes
  unsigned short* qkvb = (unsigned short*)ws;
  unsigned short* tout = (unsigned short*)ws;
  unsigned short* qkvd = (unsigned short*)(ws + SZQ);

  k_gemm<<<dim3(545, 3), 256, 0, stream>>>(x, qkvw, qkvb);
  k_dw<<<dim3(5, 17, 36), 256, 0, stream>>>(qkvb, dww, qkvd);
  k_attn<<<dim3(64, 25), 192, 0, stream>>>(qkvd, temp, tout);
  k_avgproj<<<dim3(1089), 256, 0, stream>>>(projw, tout, out);
}